// Round 7
// baseline (467.379 us; speedup 1.0000x reference)
//
#include <hip/hip_runtime.h>
#include <hip/hip_bf16.h>

typedef __bf16 bf16_t;
typedef __bf16 bf16x8 __attribute__((ext_vector_type(8)));
typedef __bf16 bf16x4 __attribute__((ext_vector_type(4)));
typedef float  f32x4  __attribute__((ext_vector_type(4)));

#define DIM   1024
#define NHEAD 16
#define HD    64
#define DFF   4096
#define SEQ   2048
#define NTOK  4096   // B*S

// lgkm-only barrier: drains LDS ops (cross-wave visibility) but leaves
// global->VGPR prefetch loads in flight across the barrier.
__device__ __forceinline__ void lgkm_barrier() {
  asm volatile("s_waitcnt lgkmcnt(0)\n\ts_barrier" ::: "memory");
}

// ------------------------------------------------------------------
// ALL six weight transposes in one launch. 12288 32x32-tile blocks.
// ------------------------------------------------------------------
struct TP {
  const float *wq, *wk, *wv, *wo, *wup, *wdown;
  bf16_t *wqkvT, *wupT, *wdownT;
};

__global__ __launch_bounds__(256)
void transpose_all(TP tp) {
  __shared__ bf16_t tile[32][33];
  const int id = blockIdx.x;
  const float* src; bf16_t* dst; int M, N, bx, by;
  if (id < 4096) {
    const int w = id >> 10, t = id & 1023;
    src = (w == 0) ? tp.wq : (w == 1) ? tp.wk : (w == 2) ? tp.wv : tp.wo;
    dst = tp.wqkvT + (long)w * DIM * DIM;
    M = DIM; N = DIM; bx = (t & 31) * 32; by = (t >> 5) * 32;
  } else if (id < 8192) {
    const int t = id - 4096;
    src = tp.wup; dst = tp.wupT; M = DIM; N = DFF;
    bx = (t & 127) * 32; by = (t >> 7) * 32;
  } else {
    const int t = id - 8192;
    src = tp.wdown; dst = tp.wdownT; M = DFF; N = DIM;
    bx = (t & 31) * 32; by = (t >> 5) * 32;
  }
  const int tt = threadIdx.x;
  const int r = tt >> 3, c4 = (tt & 7) * 4;
  f32x4 v = *(const f32x4*)&src[(long)(by + r) * N + bx + c4];
  tile[r][c4 + 0] = (bf16_t)v[0]; tile[r][c4 + 1] = (bf16_t)v[1];
  tile[r][c4 + 2] = (bf16_t)v[2]; tile[r][c4 + 3] = (bf16_t)v[3];
  __syncthreads();
  bf16x4 w4;
  w4[0] = tile[c4 + 0][r]; w4[1] = tile[c4 + 1][r];
  w4[2] = tile[c4 + 2][r]; w4[3] = tile[c4 + 3][r];
  *(bf16x4*)&dst[(long)(bx + r) * M + by + c4] = w4;
}

// ------------------------------------------------------------------
// LayerNorm (fp32 in, bf16 out) — ddof=1 std, /(sigma+eps).
// ------------------------------------------------------------------
__global__ __launch_bounds__(256)
void layernorm_k(const float* __restrict__ x, const float* __restrict__ a,
                 const float* __restrict__ b, bf16_t* __restrict__ out) {
  const int row = blockIdx.x;
  const int t   = threadIdx.x;
  const float* xr = x + (long)row * DIM;
  f32x4 v = *(const f32x4*)&xr[t * 4];
  float s1 = v[0] + v[1] + v[2] + v[3];
  float s2 = v[0]*v[0] + v[1]*v[1] + v[2]*v[2] + v[3]*v[3];
  #pragma unroll
  for (int off = 32; off > 0; off >>= 1) {
    s1 += __shfl_down(s1, off);
    s2 += __shfl_down(s2, off);
  }
  __shared__ float r1[4], r2[4];
  if ((t & 63) == 0) { r1[t >> 6] = s1; r2[t >> 6] = s2; }
  __syncthreads();
  s1 = r1[0] + r1[1] + r1[2] + r1[3];
  s2 = r2[0] + r2[1] + r2[2] + r2[3];
  const float mu = s1 * (1.0f / DIM);
  float var = (s2 - (float)DIM * mu * mu) * (1.0f / (DIM - 1));
  var = fmaxf(var, 0.0f);
  const float inv = 1.0f / (sqrtf(var) + 1e-6f);
  f32x4 av = *(const f32x4*)&a[t * 4];
  f32x4 bv = *(const f32x4*)&b[t * 4];
  bf16x4 o;
  o[0] = (bf16_t)(av[0] * (v[0] - mu) * inv + bv[0]);
  o[1] = (bf16_t)(av[1] * (v[1] - mu) * inv + bv[1]);
  o[2] = (bf16_t)(av[2] * (v[2] - mu) * inv + bv[2]);
  o[3] = (bf16_t)(av[3] * (v[3] - mu) * inv + bv[3]);
  *(bf16x4*)&out[(long)row * DIM + t * 4] = o;
}

// Fused: x1b = bf16(x + p0 + p1), h2 = LN2(x1b).  One block per row.
__global__ __launch_bounds__(256)
void reduce_wo_ln(const float* __restrict__ x, const bf16_t* __restrict__ p0,
                  const bf16_t* __restrict__ p1, const float* __restrict__ a,
                  const float* __restrict__ b, bf16_t* __restrict__ x1b,
                  bf16_t* __restrict__ h2) {
  const int row = blockIdx.x;
  const int t   = threadIdx.x;
  const long base = (long)row * DIM + t * 4;
  f32x4 v = *(const f32x4*)&x[base];
  bf16x4 pa = *(const bf16x4*)&p0[base];
  bf16x4 pb = *(const bf16x4*)&p1[base];
  bf16x4 xo;
  xo[0] = (bf16_t)(v[0] + (float)pa[0] + (float)pb[0]);
  xo[1] = (bf16_t)(v[1] + (float)pa[1] + (float)pb[1]);
  xo[2] = (bf16_t)(v[2] + (float)pa[2] + (float)pb[2]);
  xo[3] = (bf16_t)(v[3] + (float)pa[3] + (float)pb[3]);
  *(bf16x4*)&x1b[base] = xo;
  const float w0 = (float)xo[0], w1 = (float)xo[1], w2 = (float)xo[2], w3 = (float)xo[3];
  float s1 = w0 + w1 + w2 + w3;
  float s2 = w0*w0 + w1*w1 + w2*w2 + w3*w3;
  #pragma unroll
  for (int off = 32; off > 0; off >>= 1) {
    s1 += __shfl_down(s1, off);
    s2 += __shfl_down(s2, off);
  }
  __shared__ float r1[4], r2[4];
  if ((t & 63) == 0) { r1[t >> 6] = s1; r2[t >> 6] = s2; }
  __syncthreads();
  s1 = r1[0] + r1[1] + r1[2] + r1[3];
  s2 = r2[0] + r2[1] + r2[2] + r2[3];
  const float mu = s1 * (1.0f / DIM);
  float var = (s2 - (float)DIM * mu * mu) * (1.0f / (DIM - 1));
  var = fmaxf(var, 0.0f);
  const float inv = 1.0f / (sqrtf(var) + 1e-6f);
  f32x4 av = *(const f32x4*)&a[t * 4];
  f32x4 bv = *(const f32x4*)&b[t * 4];
  bf16x4 o;
  o[0] = (bf16_t)(av[0] * (w0 - mu) * inv + bv[0]);
  o[1] = (bf16_t)(av[1] * (w1 - mu) * inv + bv[1]);
  o[2] = (bf16_t)(av[2] * (w2 - mu) * inv + bv[2]);
  o[3] = (bf16_t)(av[3] * (w3 - mu) * inv + bv[3]);
  *(bf16x4*)&h2[(long)row * DIM + t * 4] = o;
}

// attn = (O0 + O1) / (l0 + l1)   (split-KV combine; in-place over O0)
__global__ __launch_bounds__(256)
void combine_att(const bf16_t* __restrict__ O1, const float* __restrict__ l0,
                 const float* __restrict__ l1, bf16_t* __restrict__ O0_attn) {
  const long i = ((long)blockIdx.x * 256 + threadIdx.x) * 4;
  const int n = (int)(i & (DIM - 1));
  const long t = i >> 10;
  const int h = n >> 6;
  const long lidx = ((t >> 11) * NHEAD + h) * SEQ + (t & (SEQ - 1));
  const float inv = 1.0f / (l0[lidx] + l1[lidx]);
  bf16x4 a = *(const bf16x4*)&O0_attn[i];
  bf16x4 b = *(const bf16x4*)&O1[i];
  bf16x4 o;
  o[0] = (bf16_t)(((float)a[0] + (float)b[0]) * inv);
  o[1] = (bf16_t)(((float)a[1] + (float)b[1]) * inv);
  o[2] = (bf16_t)(((float)a[2] + (float)b[2]) * inv);
  o[3] = (bf16_t)(((float)a[3] + (float)b[3]) * inv);
  *(bf16x4*)&O0_attn[i] = o;
}

// out = x1b + bias + p0 + p1  (fp32 out)
__global__ __launch_bounds__(256)
void reduce_fd(const bf16_t* __restrict__ x1b, const float* __restrict__ bias,
               const bf16_t* __restrict__ p0, const bf16_t* __restrict__ p1,
               float* __restrict__ out) {
  const long i = ((long)blockIdx.x * 256 + threadIdx.x) * 4;
  const int n = (int)(i & (DIM - 1));
  bf16x4 xv = *(const bf16x4*)&x1b[i];
  f32x4 bv = *(const f32x4*)&bias[n];
  bf16x4 a = *(const bf16x4*)&p0[i];
  bf16x4 b = *(const bf16x4*)&p1[i];
  f32x4 o;
  o[0] = (float)xv[0] + bv[0] + (float)a[0] + (float)b[0];
  o[1] = (float)xv[1] + bv[1] + (float)a[1] + (float)b[1];
  o[2] = (float)xv[2] + bv[2] + (float)a[2] + (float)b[2];
  o[3] = (float)xv[3] + bv[3] + (float)a[3] + (float)b[3];
  *(f32x4*)&out[i] = o;
}

// ------------------------------------------------------------------
// 128xTBN GEMM v2: reg-prefetch + dbuf LDS + lgkm-only barrier, XCD swizzle.
// ------------------------------------------------------------------
enum { EPI_QKV = 1, EPI_BIAS_RELU = 3, EPI_PART = 6 };

#define BM 128
#define BK 32

template <int EPI, int TBN>
__global__ __launch_bounds__(256)
void gemm_bt(const bf16_t* __restrict__ A, int lda,
             const bf16_t* __restrict__ BT, int ldb,
             bf16_t* __restrict__ Cb, bf16_t* __restrict__ Cb2,
             const float* __restrict__ bias,
             int M, int N, int Ks) {
  __shared__ bf16_t sA[2][BM][BK];
  __shared__ bf16_t sB[2][TBN][BK];
  const int tid  = threadIdx.x;
  int lin = blockIdx.x + gridDim.x * (blockIdx.y + gridDim.y * blockIdx.z);
  const int by_ = lin % gridDim.y; lin /= gridDim.y;
  const int bx_ = lin % gridDim.x;
  const int bz_ = lin / gridDim.x;
  const int m0   = by_ * BM;
  const int n0   = bx_ * TBN;
  const long koff = (long)bz_ * Ks;
  const int lane = tid & 63, wave = tid >> 6;
  constexpr int MI = (TBN == 128) ? 4 : 2;
  const int wm = (TBN == 128) ? (wave >> 1) * 64 : wave * 32;
  const int wn = (TBN == 128) ? (wave & 1) * 64 : 0;
  const int fm = lane & 15, fq = lane >> 4;

  const int lr = lane >> 2, lc = (lane & 3) * 8;
  const bf16_t* gA0 = &A[(long)(m0 + wave * 32 + lr) * lda + koff + lc];
  const bf16_t* gA1 = gA0 + 16 * (long)lda;
  const int brow = (TBN == 128) ? wave * 32 : wave * 16;
  const bf16_t* gB0 = &BT[(long)(n0 + brow + lr) * ldb + koff + lc];
  const bf16_t* gB1 = gB0 + 16 * (long)ldb;   // used only when TBN==128

  f32x4 acc[MI][4] = {};
  bf16x8 rA0, rA1, rB0, rB1;

  rA0 = *(const bf16x8*)gA0;
  rA1 = *(const bf16x8*)gA1;
  rB0 = *(const bf16x8*)gB0;
  if constexpr (TBN == 128) rB1 = *(const bf16x8*)gB1;
  gA0 += BK; gA1 += BK; gB0 += BK; gB1 += BK;
  *(bf16x8*)&sA[0][wave * 32 + lr][lc]      = rA0;
  *(bf16x8*)&sA[0][wave * 32 + 16 + lr][lc] = rA1;
  *(bf16x8*)&sB[0][brow + lr][lc]           = rB0;
  if constexpr (TBN == 128) *(bf16x8*)&sB[0][wave * 32 + 16 + lr][lc] = rB1;
  if (BK < Ks) {
    rA0 = *(const bf16x8*)gA0;
    rA1 = *(const bf16x8*)gA1;
    rB0 = *(const bf16x8*)gB0;
    if constexpr (TBN == 128) rB1 = *(const bf16x8*)gB1;
    gA0 += BK; gA1 += BK; gB0 += BK; gB1 += BK;
  }
  __syncthreads();

  int p = 0;
  for (int k0 = 0; k0 < Ks; k0 += BK, p ^= 1) {
    if (k0 + BK < Ks) {
      *(bf16x8*)&sA[p ^ 1][wave * 32 + lr][lc]      = rA0;
      *(bf16x8*)&sA[p ^ 1][wave * 32 + 16 + lr][lc] = rA1;
      *(bf16x8*)&sB[p ^ 1][brow + lr][lc]           = rB0;
      if constexpr (TBN == 128) *(bf16x8*)&sB[p ^ 1][wave * 32 + 16 + lr][lc] = rB1;
      if (k0 + 2 * BK < Ks) {
        rA0 = *(const bf16x8*)gA0;
        rA1 = *(const bf16x8*)gA1;
        rB0 = *(const bf16x8*)gB0;
        if constexpr (TBN == 128) rB1 = *(const bf16x8*)gB1;
        gA0 += BK; gA1 += BK; gB0 += BK; gB1 += BK;
      }
    }
    bf16x8 af[MI], bfr[4];
    #pragma unroll
    for (int i = 0; i < MI; i++) af[i]  = *(const bf16x8*)&sA[p][wm + i * 16 + fm][fq * 8];
    #pragma unroll
    for (int j = 0; j < 4; j++)  bfr[j] = *(const bf16x8*)&sB[p][wn + j * 16 + fm][fq * 8];
    #pragma unroll
    for (int i = 0; i < MI; i++)
      #pragma unroll
      for (int j = 0; j < 4; j++)
        acc[i][j] = __builtin_amdgcn_mfma_f32_16x16x32_bf16(af[i], bfr[j], acc[i][j], 0, 0, 0);
    lgkm_barrier();
  }

  #pragma unroll
  for (int i = 0; i < MI; i++) {
    #pragma unroll
    for (int j = 0; j < 4; j++) {
      const int mb = m0 + wm + i * 16 + fq * 4;
      const int n  = n0 + wn + j * 16 + fm;
      #pragma unroll
      for (int r = 0; r < 4; r++) {
        const int m = mb + r;
        float vv = acc[i][j][r];
        if constexpr (EPI == EPI_QKV) {
          const int mat = n >> 10, h_ = (n >> 6) & 15, d_ = n & 63;
          const int b_ = m >> 11, s_ = m & 2047;
          if (mat == 2) {
            Cb2[((long)(b_ * NHEAD + h_) * HD + d_) * SEQ + s_] = (bf16_t)vv;
          } else {
            Cb[(long)mat * (32L * SEQ * HD) + (((long)(b_ * NHEAD + h_)) * SEQ + s_) * HD + d_] = (bf16_t)vv;
          }
        } else if constexpr (EPI == EPI_BIAS_RELU) {
          Cb[(long)m * N + n] = (bf16_t)fmaxf(vv + bias[n], 0.0f);
        } else {  // EPI_PART
          bf16_t* P = bz_ ? Cb2 : Cb;
          P[(long)m * N + n] = (bf16_t)vv;
        }
      }
    }
  }
}

// ------------------------------------------------------------------
// Flash attention v7: direct-from-L2 fragment loads, NO LDS, NO barriers.
// Rationale (round-3 counters): latency-bound (MfmaUtil 22 / VALUBusy 29 /
// HBM 5.9 / Occ 22), K/V per XCD ~1 MB = L2-resident, and all 4 waves of a
// block read IDENTICAL K/V addresses (L1 serves 3/4). LDS staging was pure
// overhead: 2 barriers + staging VALU + 1.05M bank-conflict cycles per
// dispatch. Fragment mappings derived from the (passing) v6 swizzle net out
// to identity:
//   aK(h2) lane(fm,fq) = K[kv0 + (fm>>2)*8 + h2*4 + (fm&3)][kk*32+fq*8..]
//   P-frag slot k      = P[q][kv0 + k]            (identity)
//   bV(jd) lane(fm,fq) = vt[jd*16+fm][kv0 + fq*8..+8]   (one 16B load)
// so the MFMA operand order (and thus numerics) is unchanged from v6.
// Per 32-kv step/wave: 4x16B K + 4x16B V loads, 8 QK + 2 rowsum + 8 PV
// MFMAs, 16 exp2. Pointers advance by constants; K offsets fold into
// 13-bit load immediates (0/64/512/576 B).
// ------------------------------------------------------------------
__global__ __launch_bounds__(256)
void flash_attn(const bf16_t* __restrict__ q, const bf16_t* __restrict__ k,
                const bf16_t* __restrict__ vt,
                bf16_t* __restrict__ O0, bf16_t* __restrict__ O1,
                float* __restrict__ l0, float* __restrict__ l1) {
  const int tid  = threadIdx.x;
  const int bh   = blockIdx.x & 31, qb = blockIdx.x >> 5;   // XCD-cluster
  const int b    = bh >> 4, h = bh & 15;
  const int lane = tid & 63, wave = tid >> 6;
  const int fm   = lane & 15, fq = lane >> 4;
  const int qw0  = qb * 128 + wave * 32;
  const int kvbase = blockIdx.y * (SEQ / 2);
  bf16_t* Op = blockIdx.y ? O1 : O0;
  float*  lp = blockIdx.y ? l1 : l0;

  const bf16_t* qh  = q  + (long)bh * SEQ * HD;
  const bf16_t* kh  = k  + (long)bh * SEQ * HD;
  const bf16_t* vth = vt + (long)bh * HD * SEQ;

  // Q prescaled by (1/8)*log2(e): scores feed exp2 directly
  bf16x8 bQ[2][2];
  #pragma unroll
  for (int qt = 0; qt < 2; qt++)
    #pragma unroll
    for (int kk = 0; kk < 2; kk++) {
      bf16x8 v = *(const bf16x8*)&qh[(long)(qw0 + qt * 16 + fm) * HD + kk * 32 + fq * 8];
      #pragma unroll
      for (int e = 0; e < 8; e++) v[e] = (bf16_t)((float)v[e] * 0.18033688f);
      bQ[qt][kk] = v;
    }

  // ones-fragment for MFMA row-sums (kv-permutation-invariant)
  bf16x8 ones;
  #pragma unroll
  for (int e = 0; e < 8; e++) ones[e] = (bf16_t)1.0f;

  // K fragment pointer: row permutation rbase = (fm>>2)*8 + (fm&3);
  // h2 adds +4 rows (512B), kk adds +32 elems (64B) — both fold into imms.
  const int rbase = ((fm >> 2) << 3) | (fm & 3);
  const bf16_t* pK  = kh + (long)(kvbase + rbase) * HD + fq * 8;
  // V^T fragment pointers, one per 16-d block (jd)
  const bf16_t* pV0 = vth + (long)fm * SEQ + kvbase + fq * 8;
  const bf16_t* pV1 = pV0 + 16L * SEQ;
  const bf16_t* pV2 = pV0 + 32L * SEQ;
  const bf16_t* pV3 = pV0 + 48L * SEQ;

  f32x4 oA[4] = {}, oB[4] = {};
  f32x4 oLA = {}, oLB = {};

  for (int it = 0; it < (SEQ / 2) / 32; it++) {
    bf16x8 aK00 = *(const bf16x8*)(pK);            // h2=0, d 0..31
    bf16x8 aK01 = *(const bf16x8*)(pK + 32);       // h2=0, d 32..63
    bf16x8 aK10 = *(const bf16x8*)(pK + 4 * HD);   // h2=1, d 0..31
    bf16x8 aK11 = *(const bf16x8*)(pK + 4 * HD + 32);
    bf16x8 bV0  = *(const bf16x8*)(pV0);
    bf16x8 bV1  = *(const bf16x8*)(pV1);
    bf16x8 bV2  = *(const bf16x8*)(pV2);
    bf16x8 bV3  = *(const bf16x8*)(pV3);
    pK += 32 * HD; pV0 += 32; pV1 += 32; pV2 += 32; pV3 += 32;

    f32x4 stA0 = {}, stA1 = {}, stB0 = {}, stB1 = {};
    stA0 = __builtin_amdgcn_mfma_f32_16x16x32_bf16(aK00, bQ[0][0], stA0, 0, 0, 0);
    stA0 = __builtin_amdgcn_mfma_f32_16x16x32_bf16(aK01, bQ[0][1], stA0, 0, 0, 0);
    stA1 = __builtin_amdgcn_mfma_f32_16x16x32_bf16(aK10, bQ[0][0], stA1, 0, 0, 0);
    stA1 = __builtin_amdgcn_mfma_f32_16x16x32_bf16(aK11, bQ[0][1], stA1, 0, 0, 0);
    stB0 = __builtin_amdgcn_mfma_f32_16x16x32_bf16(aK00, bQ[1][0], stB0, 0, 0, 0);
    stB0 = __builtin_amdgcn_mfma_f32_16x16x32_bf16(aK01, bQ[1][1], stB0, 0, 0, 0);
    stB1 = __builtin_amdgcn_mfma_f32_16x16x32_bf16(aK10, bQ[1][0], stB1, 0, 0, 0);
    stB1 = __builtin_amdgcn_mfma_f32_16x16x32_bf16(aK11, bQ[1][1], stB1, 0, 0, 0);

    bf16x8 pA, pB;
    #pragma unroll
    for (int r = 0; r < 4; r++) {
      pA[r]     = (bf16_t)__builtin_amdgcn_exp2f(stA0[r]);
      pA[4 + r] = (bf16_t)__builtin_amdgcn_exp2f(stA1[r]);
      pB[r]     = (bf16_t)__builtin_amdgcn_exp2f(stB0[r]);
      pB[4 + r] = (bf16_t)__builtin_amdgcn_exp2f(stB1[r]);
    }

    // row sums on the matrix pipe
    oLA = __builtin_amdgcn_mfma_f32_16x16x32_bf16(pA, ones, oLA, 0, 0, 0);
    oLB = __builtin_amdgcn_mfma_f32_16x16x32_bf16(pB, ones, oLB, 0, 0, 0);

    oA[0] = __builtin_amdgcn_mfma_f32_16x16x32_bf16(pA, bV0, oA[0], 0, 0, 0);
    oB[0] = __builtin_amdgcn_mfma_f32_16x16x32_bf16(pB, bV0, oB[0], 0, 0, 0);
    oA[1] = __builtin_amdgcn_mfma_f32_16x16x32_bf16(pA, bV1, oA[1], 0, 0, 0);
    oB[1] = __builtin_amdgcn_mfma_f32_16x16x32_bf16(pB, bV1, oB[1], 0, 0, 0);
    oA[2] = __builtin_amdgcn_mfma_f32_16x16x32_bf16(pA, bV2, oA[2], 0, 0, 0);
    oB[2] = __builtin_amdgcn_mfma_f32_16x16x32_bf16(pB, bV2, oB[2], 0, 0, 0);
    oA[3] = __builtin_amdgcn_mfma_f32_16x16x32_bf16(pA, bV3, oA[3], 0, 0, 0);
    oB[3] = __builtin_amdgcn_mfma_f32_16x16x32_bf16(pB, bV3, oB[3], 0, 0, 0);
  }

  // oLA/oLB: D[q][c] with all 16 cols equal; lane fm==0 holds q = fq*4+r
  if (fm == 0) {
    #pragma unroll
    for (int r = 0; r < 4; r++) {
      lp[(long)bh * SEQ + qw0 + fq * 4 + r]      = oLA[r];
      lp[(long)bh * SEQ + qw0 + 16 + fq * 4 + r] = oLB[r];
    }
  }

  #pragma unroll
  for (int r = 0; r < 4; r++) {
    const long rowA = ((long)b * SEQ + qw0 + fq * 4 + r) * DIM + h * HD;
    const long rowB = rowA + 16L * DIM;
    #pragma unroll
    for (int jd = 0; jd < 4; jd++) {
      Op[rowA + jd * 16 + fm] = (bf16_t)oA[jd][r];
      Op[rowB + jd * 16 + fm] = (bf16_t)oB[jd][r];
    }
  }
}

// ------------------------------------------------------------------
// ws layout — 65 MB (unchanged):
// ------------------------------------------------------------------
extern "C" void kernel_launch(void* const* d_in, const int* in_sizes, int n_in,
                              void* d_out, int out_size, void* d_ws, size_t ws_size,
                              hipStream_t stream) {
  (void)in_sizes; (void)n_in; (void)out_size; (void)ws_size;
  const float* x      = (const float*)d_in[0];
  const float* wq     = (const float*)d_in[2];
  const float* wk     = (const float*)d_in[3];
  const float* wv     = (const float*)d_in[4];
  const float* wo     = (const float*)d_in[5];
  const float* w_up   = (const float*)d_in[6];
  const float* b_up   = (const float*)d_in[7];
  const float* w_down = (const float*)d_in[8];
  const float* b_down = (const float*)d_in[9];
  const float* ln1a   = (const float*)d_in[10];
  const float* ln1b   = (const float*)d_in[11];
  const float* ln2a   = (const float*)d_in[12];
  const float* ln2b   = (const float*)d_in[13];

  char* ws = (char*)d_ws;
  const size_t MB = 1ull << 20;
  const size_t KB = 1ull << 10;
  float*  l0     = (float*)(ws);              // 256 KB
  float*  l1     = (float*)(ws + 256 * KB);   // 256 KB
  bf16_t* wqkvT  = (bf16_t*)(ws + 512 * KB);  // 6 MB
  bf16_t* woT    = (bf16_t*)(ws + 512 * KB + 6 * MB);  // 2 MB
  bf16_t* h      = (bf16_t*)(ws + 9 * MB);
  bf16_t* O0     = (bf16_t*)(ws + 9 * MB);
  bf16_t* attn   = (bf16_t*)(ws + 9 * MB);
  bf16_t* qkv    = (bf16_t*)(ws + 17 * MB);
  bf16_t* qd     = (bf16_t*)(ws + 17 * MB);
  bf16_t* kd     = (bf16_t*)(ws + 25 * MB);
  bf16_t* vtd    = (bf16_t*)(ws + 33 * MB);
  bf16_t* O1     = (bf16_t*)(ws + 41 * MB);
  bf16_t* p0_wo  = (bf16_t*)(ws + 17 * MB);
  bf16_t* p1_wo  = (bf16_t*)(ws + 25 * MB);
  bf16_t* x1b    = (bf16_t*)(ws + 41 * MB);
  bf16_t* h2     = (bf16_t*)(ws);
  bf16_t* wdownT = (bf16_t*)(ws + 49 * MB);
  bf16_t* wupT   = (bf16_t*)(ws + 57 * MB);
  bf16_t* ff1    = (bf16_t*)(ws + 9 * MB);
  bf16_t* p0_fd  = (bf16_t*)(ws);
  bf16_t* p1_fd  = (bf16_t*)(ws + 57 * MB);
  float*  outp   = (float*)d_out;

  const dim3 T(256);
  TP tp{wq, wk, wv, wo, w_up, w_down, wqkvT, wupT, wdownT};
  transpose_all<<<dim3(12288), T, 0, stream>>>(tp);

  layernorm_k<<<dim3(4096), T, 0, stream>>>(x, ln1a, ln1b, h);
  gemm_bt<EPI_QKV, 128><<<dim3(24, 32), T, 0, stream>>>(h, DIM, wqkvT, DIM, qkv, vtd,
                                                        nullptr, NTOK, 3072, DIM);
  flash_attn<<<dim3(512, 2), T, 0, stream>>>(qd, kd, vtd, O0, O1, l0, l1);
  combine_att<<<dim3(NTOK * DIM / 1024), T, 0, stream>>>(O1, l0, l1, attn);
  gemm_bt<EPI_PART, 64><<<dim3(16, 32, 2), T, 0, stream>>>(attn, DIM, woT, DIM, p0_wo, p1_wo,
                                                           nullptr, NTOK, DIM, DIM / 2);
  reduce_wo_ln<<<dim3(4096), T, 0, stream>>>(x, p0_wo, p1_wo, ln2a, ln2b, x1b, h2);
  gemm_bt<EPI_BIAS_RELU, 128><<<dim3(32, 32), T, 0, stream>>>(h2, DIM, wupT, DIM, ff1, nullptr,
                                                              b_up, NTOK, DFF, DIM);
  gemm_bt<EPI_PART, 64><<<dim3(16, 32, 2), T, 0, stream>>>(ff1, DFF, wdownT, DFF, p0_fd, p1_fd,
                                                           nullptr, NTOK, DIM, DFF / 2);
  reduce_fd<<<dim3(NTOK * DIM / 1024), T, 0, stream>>>(x1b, b_down, p0_fd, p1_fd, outp);
}

// Round 11
// 368.256 us; speedup vs baseline: 1.2692x; 1.2692x over previous
//
#include <hip/hip_runtime.h>
#include <hip/hip_bf16.h>

typedef __bf16 bf16_t;
typedef __bf16 bf16x8 __attribute__((ext_vector_type(8)));
typedef __bf16 bf16x4 __attribute__((ext_vector_type(4)));
typedef float  f32x4  __attribute__((ext_vector_type(4)));

#define DIM   1024
#define NHEAD 16
#define HD    64
#define DFF   4096
#define SEQ   2048
#define NTOK  4096   // B*S

// lgkm-only barrier: drains LDS ops (cross-wave visibility) but leaves
// global->VGPR prefetch loads in flight across the barrier.
__device__ __forceinline__ void lgkm_barrier() {
  asm volatile("s_waitcnt lgkmcnt(0)\n\ts_barrier" ::: "memory");
}

// ------------------------------------------------------------------
// ALL six weight transposes in one launch. 12288 32x32-tile blocks.
// ------------------------------------------------------------------
struct TP {
  const float *wq, *wk, *wv, *wo, *wup, *wdown;
  bf16_t *wqkvT, *wupT, *wdownT;
};

__global__ __launch_bounds__(256)
void transpose_all(TP tp) {
  __shared__ bf16_t tile[32][33];
  const int id = blockIdx.x;
  const float* src; bf16_t* dst; int M, N, bx, by;
  if (id < 4096) {
    const int w = id >> 10, t = id & 1023;
    src = (w == 0) ? tp.wq : (w == 1) ? tp.wk : (w == 2) ? tp.wv : tp.wo;
    dst = tp.wqkvT + (long)w * DIM * DIM;
    M = DIM; N = DIM; bx = (t & 31) * 32; by = (t >> 5) * 32;
  } else if (id < 8192) {
    const int t = id - 4096;
    src = tp.wup; dst = tp.wupT; M = DIM; N = DFF;
    bx = (t & 127) * 32; by = (t >> 7) * 32;
  } else {
    const int t = id - 8192;
    src = tp.wdown; dst = tp.wdownT; M = DFF; N = DIM;
    bx = (t & 31) * 32; by = (t >> 5) * 32;
  }
  const int tt = threadIdx.x;
  const int r = tt >> 3, c4 = (tt & 7) * 4;
  f32x4 v = *(const f32x4*)&src[(long)(by + r) * N + bx + c4];
  tile[r][c4 + 0] = (bf16_t)v[0]; tile[r][c4 + 1] = (bf16_t)v[1];
  tile[r][c4 + 2] = (bf16_t)v[2]; tile[r][c4 + 3] = (bf16_t)v[3];
  __syncthreads();
  bf16x4 w4;
  w4[0] = tile[c4 + 0][r]; w4[1] = tile[c4 + 1][r];
  w4[2] = tile[c4 + 2][r]; w4[3] = tile[c4 + 3][r];
  *(bf16x4*)&dst[(long)(bx + r) * M + by + c4] = w4;
}

// ------------------------------------------------------------------
// LayerNorm (fp32 in, bf16 out) — ddof=1 std, /(sigma+eps).
// ------------------------------------------------------------------
__global__ __launch_bounds__(256)
void layernorm_k(const float* __restrict__ x, const float* __restrict__ a,
                 const float* __restrict__ b, bf16_t* __restrict__ out) {
  const int row = blockIdx.x;
  const int t   = threadIdx.x;
  const float* xr = x + (long)row * DIM;
  f32x4 v = *(const f32x4*)&xr[t * 4];
  float s1 = v[0] + v[1] + v[2] + v[3];
  float s2 = v[0]*v[0] + v[1]*v[1] + v[2]*v[2] + v[3]*v[3];
  #pragma unroll
  for (int off = 32; off > 0; off >>= 1) {
    s1 += __shfl_down(s1, off);
    s2 += __shfl_down(s2, off);
  }
  __shared__ float r1[4], r2[4];
  if ((t & 63) == 0) { r1[t >> 6] = s1; r2[t >> 6] = s2; }
  __syncthreads();
  s1 = r1[0] + r1[1] + r1[2] + r1[3];
  s2 = r2[0] + r2[1] + r2[2] + r2[3];
  const float mu = s1 * (1.0f / DIM);
  float var = (s2 - (float)DIM * mu * mu) * (1.0f / (DIM - 1));
  var = fmaxf(var, 0.0f);
  const float inv = 1.0f / (sqrtf(var) + 1e-6f);
  f32x4 av = *(const f32x4*)&a[t * 4];
  f32x4 bv = *(const f32x4*)&b[t * 4];
  bf16x4 o;
  o[0] = (bf16_t)(av[0] * (v[0] - mu) * inv + bv[0]);
  o[1] = (bf16_t)(av[1] * (v[1] - mu) * inv + bv[1]);
  o[2] = (bf16_t)(av[2] * (v[2] - mu) * inv + bv[2]);
  o[3] = (bf16_t)(av[3] * (v[3] - mu) * inv + bv[3]);
  *(bf16x4*)&out[(long)row * DIM + t * 4] = o;
}

// Fused: x1b = bf16(x + p0 + p1), h2 = LN2(x1b).  One block per row.
__global__ __launch_bounds__(256)
void reduce_wo_ln(const float* __restrict__ x, const bf16_t* __restrict__ p0,
                  const bf16_t* __restrict__ p1, const float* __restrict__ a,
                  const float* __restrict__ b, bf16_t* __restrict__ x1b,
                  bf16_t* __restrict__ h2) {
  const int row = blockIdx.x;
  const int t   = threadIdx.x;
  const long base = (long)row * DIM + t * 4;
  f32x4 v = *(const f32x4*)&x[base];
  bf16x4 pa = *(const bf16x4*)&p0[base];
  bf16x4 pb = *(const bf16x4*)&p1[base];
  bf16x4 xo;
  xo[0] = (bf16_t)(v[0] + (float)pa[0] + (float)pb[0]);
  xo[1] = (bf16_t)(v[1] + (float)pa[1] + (float)pb[1]);
  xo[2] = (bf16_t)(v[2] + (float)pa[2] + (float)pb[2]);
  xo[3] = (bf16_t)(v[3] + (float)pa[3] + (float)pb[3]);
  *(bf16x4*)&x1b[base] = xo;
  const float w0 = (float)xo[0], w1 = (float)xo[1], w2 = (float)xo[2], w3 = (float)xo[3];
  float s1 = w0 + w1 + w2 + w3;
  float s2 = w0*w0 + w1*w1 + w2*w2 + w3*w3;
  #pragma unroll
  for (int off = 32; off > 0; off >>= 1) {
    s1 += __shfl_down(s1, off);
    s2 += __shfl_down(s2, off);
  }
  __shared__ float r1[4], r2[4];
  if ((t & 63) == 0) { r1[t >> 6] = s1; r2[t >> 6] = s2; }
  __syncthreads();
  s1 = r1[0] + r1[1] + r1[2] + r1[3];
  s2 = r2[0] + r2[1] + r2[2] + r2[3];
  const float mu = s1 * (1.0f / DIM);
  float var = (s2 - (float)DIM * mu * mu) * (1.0f / (DIM - 1));
  var = fmaxf(var, 0.0f);
  const float inv = 1.0f / (sqrtf(var) + 1e-6f);
  f32x4 av = *(const f32x4*)&a[t * 4];
  f32x4 bv = *(const f32x4*)&b[t * 4];
  bf16x4 o;
  o[0] = (bf16_t)(av[0] * (w0 - mu) * inv + bv[0]);
  o[1] = (bf16_t)(av[1] * (w1 - mu) * inv + bv[1]);
  o[2] = (bf16_t)(av[2] * (w2 - mu) * inv + bv[2]);
  o[3] = (bf16_t)(av[3] * (w3 - mu) * inv + bv[3]);
  *(bf16x4*)&h2[(long)row * DIM + t * 4] = o;
}

// attn = (O0 + O1) / (l0 + l1)   (split-KV combine; in-place over O0)
__global__ __launch_bounds__(256)
void combine_att(const bf16_t* __restrict__ O1, const float* __restrict__ l0,
                 const float* __restrict__ l1, bf16_t* __restrict__ O0_attn) {
  const long i = ((long)blockIdx.x * 256 + threadIdx.x) * 4;
  const int n = (int)(i & (DIM - 1));
  const long t = i >> 10;
  const int h = n >> 6;
  const long lidx = ((t >> 11) * NHEAD + h) * SEQ + (t & (SEQ - 1));
  const float inv = 1.0f / (l0[lidx] + l1[lidx]);
  bf16x4 a = *(const bf16x4*)&O0_attn[i];
  bf16x4 b = *(const bf16x4*)&O1[i];
  bf16x4 o;
  o[0] = (bf16_t)(((float)a[0] + (float)b[0]) * inv);
  o[1] = (bf16_t)(((float)a[1] + (float)b[1]) * inv);
  o[2] = (bf16_t)(((float)a[2] + (float)b[2]) * inv);
  o[3] = (bf16_t)(((float)a[3] + (float)b[3]) * inv);
  *(bf16x4*)&O0_attn[i] = o;
}

// out = x1b + bias + p0 + p1  (fp32 out)
__global__ __launch_bounds__(256)
void reduce_fd(const bf16_t* __restrict__ x1b, const float* __restrict__ bias,
               const bf16_t* __restrict__ p0, const bf16_t* __restrict__ p1,
               float* __restrict__ out) {
  const long i = ((long)blockIdx.x * 256 + threadIdx.x) * 4;
  const int n = (int)(i & (DIM - 1));
  bf16x4 xv = *(const bf16x4*)&x1b[i];
  f32x4 bv = *(const f32x4*)&bias[n];
  bf16x4 a = *(const bf16x4*)&p0[i];
  bf16x4 b = *(const bf16x4*)&p1[i];
  f32x4 o;
  o[0] = (float)xv[0] + bv[0] + (float)a[0] + (float)b[0];
  o[1] = (float)xv[1] + bv[1] + (float)a[1] + (float)b[1];
  o[2] = (float)xv[2] + bv[2] + (float)a[2] + (float)b[2];
  o[3] = (float)xv[3] + bv[3] + (float)a[3] + (float)b[3];
  *(f32x4*)&out[i] = o;
}

// ------------------------------------------------------------------
// 128xTBN GEMM v2: reg-prefetch + dbuf LDS + lgkm-only barrier, XCD swizzle.
// ------------------------------------------------------------------
enum { EPI_QKV = 1, EPI_BIAS_RELU = 3, EPI_PART = 6 };

#define BM 128
#define BK 32

template <int EPI, int TBN>
__global__ __launch_bounds__(256)
void gemm_bt(const bf16_t* __restrict__ A, int lda,
             const bf16_t* __restrict__ BT, int ldb,
             bf16_t* __restrict__ Cb, bf16_t* __restrict__ Cb2,
             const float* __restrict__ bias,
             int M, int N, int Ks) {
  __shared__ bf16_t sA[2][BM][BK];
  __shared__ bf16_t sB[2][TBN][BK];
  const int tid  = threadIdx.x;
  int lin = blockIdx.x + gridDim.x * (blockIdx.y + gridDim.y * blockIdx.z);
  const int by_ = lin % gridDim.y; lin /= gridDim.y;
  const int bx_ = lin % gridDim.x;
  const int bz_ = lin / gridDim.x;
  const int m0   = by_ * BM;
  const int n0   = bx_ * TBN;
  const long koff = (long)bz_ * Ks;
  const int lane = tid & 63, wave = tid >> 6;
  constexpr int MI = (TBN == 128) ? 4 : 2;
  const int wm = (TBN == 128) ? (wave >> 1) * 64 : wave * 32;
  const int wn = (TBN == 128) ? (wave & 1) * 64 : 0;
  const int fm = lane & 15, fq = lane >> 4;

  const int lr = lane >> 2, lc = (lane & 3) * 8;
  const bf16_t* gA0 = &A[(long)(m0 + wave * 32 + lr) * lda + koff + lc];
  const bf16_t* gA1 = gA0 + 16 * (long)lda;
  const int brow = (TBN == 128) ? wave * 32 : wave * 16;
  const bf16_t* gB0 = &BT[(long)(n0 + brow + lr) * ldb + koff + lc];
  const bf16_t* gB1 = gB0 + 16 * (long)ldb;   // used only when TBN==128

  f32x4 acc[MI][4] = {};
  bf16x8 rA0, rA1, rB0, rB1;

  rA0 = *(const bf16x8*)gA0;
  rA1 = *(const bf16x8*)gA1;
  rB0 = *(const bf16x8*)gB0;
  if constexpr (TBN == 128) rB1 = *(const bf16x8*)gB1;
  gA0 += BK; gA1 += BK; gB0 += BK; gB1 += BK;
  *(bf16x8*)&sA[0][wave * 32 + lr][lc]      = rA0;
  *(bf16x8*)&sA[0][wave * 32 + 16 + lr][lc] = rA1;
  *(bf16x8*)&sB[0][brow + lr][lc]           = rB0;
  if constexpr (TBN == 128) *(bf16x8*)&sB[0][wave * 32 + 16 + lr][lc] = rB1;
  if (BK < Ks) {
    rA0 = *(const bf16x8*)gA0;
    rA1 = *(const bf16x8*)gA1;
    rB0 = *(const bf16x8*)gB0;
    if constexpr (TBN == 128) rB1 = *(const bf16x8*)gB1;
    gA0 += BK; gA1 += BK; gB0 += BK; gB1 += BK;
  }
  __syncthreads();

  int p = 0;
  for (int k0 = 0; k0 < Ks; k0 += BK, p ^= 1) {
    if (k0 + BK < Ks) {
      *(bf16x8*)&sA[p ^ 1][wave * 32 + lr][lc]      = rA0;
      *(bf16x8*)&sA[p ^ 1][wave * 32 + 16 + lr][lc] = rA1;
      *(bf16x8*)&sB[p ^ 1][brow + lr][lc]           = rB0;
      if constexpr (TBN == 128) *(bf16x8*)&sB[p ^ 1][wave * 32 + 16 + lr][lc] = rB1;
      if (k0 + 2 * BK < Ks) {
        rA0 = *(const bf16x8*)gA0;
        rA1 = *(const bf16x8*)gA1;
        rB0 = *(const bf16x8*)gB0;
        if constexpr (TBN == 128) rB1 = *(const bf16x8*)gB1;
        gA0 += BK; gA1 += BK; gB0 += BK; gB1 += BK;
      }
    }
    bf16x8 af[MI], bfr[4];
    #pragma unroll
    for (int i = 0; i < MI; i++) af[i]  = *(const bf16x8*)&sA[p][wm + i * 16 + fm][fq * 8];
    #pragma unroll
    for (int j = 0; j < 4; j++)  bfr[j] = *(const bf16x8*)&sB[p][wn + j * 16 + fm][fq * 8];
    #pragma unroll
    for (int i = 0; i < MI; i++)
      #pragma unroll
      for (int j = 0; j < 4; j++)
        acc[i][j] = __builtin_amdgcn_mfma_f32_16x16x32_bf16(af[i], bfr[j], acc[i][j], 0, 0, 0);
    lgkm_barrier();
  }

  #pragma unroll
  for (int i = 0; i < MI; i++) {
    #pragma unroll
    for (int j = 0; j < 4; j++) {
      const int mb = m0 + wm + i * 16 + fq * 4;
      const int n  = n0 + wn + j * 16 + fm;
      #pragma unroll
      for (int r = 0; r < 4; r++) {
        const int m = mb + r;
        float vv = acc[i][j][r];
        if constexpr (EPI == EPI_QKV) {
          const int mat = n >> 10, h_ = (n >> 6) & 15, d_ = n & 63;
          const int b_ = m >> 11, s_ = m & 2047;
          if (mat == 2) {
            Cb2[((long)(b_ * NHEAD + h_) * HD + d_) * SEQ + s_] = (bf16_t)vv;
          } else {
            Cb[(long)mat * (32L * SEQ * HD) + (((long)(b_ * NHEAD + h_)) * SEQ + s_) * HD + d_] = (bf16_t)vv;
          }
        } else if constexpr (EPI == EPI_BIAS_RELU) {
          Cb[(long)m * N + n] = (bf16_t)fmaxf(vv + bias[n], 0.0f);
        } else {  // EPI_PART
          bf16_t* P = bz_ ? Cb2 : Cb;
          P[(long)m * N + n] = (bf16_t)vv;
        }
      }
    }
  }
}

// ------------------------------------------------------------------
// Flash attention v8 = v6 LDS-staging structure (known-good 68.8 us,
// bit-identical staging data/order) + T14 next-tile register prefetch.
// Round-7 postmortem: v7 (no LDS, direct loads) collapsed MfmaUtil to
// 9.6% — per-32kv-step load latency serially exposed 64x/wave. The LDS
// tile staging IS the latency amortizer; what v6 lacked was overlap of
// the NEXT tile's global loads with the CURRENT tile's compute.
// v8 staging-address algebra (tid<256 => phase index p enters linearly:
// u=p for K, jd=p for V; verified against the HW-validated v6/v7 maps):
//   K src  = base + p*32*HD,  K dst = oK0 + p*2048 elems
//   V src  = base + p*16*SEQ, V dst = oV[p] (4 compile-time ints)
// Loop: sync -> ds_write rK/rV (tile it) -> issue loads tile it+1 ->
// sync -> compute. Loads get the full compute phase (~1500 cy) to land.
// NO launch_bounds cap (round-1 lesson: cap+oversized live set = 470 MB
// scratch). Live set ~105-125 VGPR, under the 128 occupancy cliff.
// ------------------------------------------------------------------
#define KVT 128

__device__ __forceinline__ int swz(int grp, int slot) {
  return (grp * 64 + (slot ^ ((slot >> 3) & 7) ^ (grp & 1))) * 8;
}

__global__ __launch_bounds__(256)
void flash_attn(const bf16_t* __restrict__ q, const bf16_t* __restrict__ k,
                const bf16_t* __restrict__ vt,
                bf16_t* __restrict__ O0, bf16_t* __restrict__ O1,
                float* __restrict__ l0, float* __restrict__ l1) {
  __shared__ bf16_t sK[16 * 64 * 8];   // 16 KB
  __shared__ bf16_t sV[16 * 64 * 8];   // 16 KB

  const int tid  = threadIdx.x;
  const int bh   = blockIdx.x & 31, qb = blockIdx.x >> 5;   // XCD-cluster
  const int b    = bh >> 4, h = bh & 15;
  const int lane = tid & 63, wave = tid >> 6;
  const int fm   = lane & 15, fq = lane >> 4;
  const int qw0  = qb * 128 + wave * 32;
  const int kvbase = blockIdx.y * (SEQ / 2);
  bf16_t* Op = blockIdx.y ? O1 : O0;
  float*  lp = blockIdx.y ? l1 : l0;

  const bf16_t* qh  = q  + (long)bh * SEQ * HD;
  const bf16_t* kh  = k  + (long)bh * SEQ * HD;
  const bf16_t* vth = vt + (long)bh * HD * SEQ;

  // Q prescaled by (1/8)*log2(e): scores feed exp2 directly
  bf16x8 bQ[2][2];
  #pragma unroll
  for (int qt = 0; qt < 2; qt++)
    #pragma unroll
    for (int kk = 0; kk < 2; kk++) {
      bf16x8 v = *(const bf16x8*)&qh[(long)(qw0 + qt * 16 + fm) * HD + kk * 32 + fq * 8];
      #pragma unroll
      for (int e = 0; e < 8; e++) v[e] = (bf16_t)((float)v[e] * 0.18033688f);
      bQ[qt][kk] = v;
    }

  // ones-fragment for MFMA row-sums (kv-permutation-invariant)
  bf16x8 ones;
  #pragma unroll
  for (int e = 0; e < 8; e++) ones[e] = (bf16_t)1.0f;

  // ---- loop-invariant staging addresses (v6 maps with u=p, jd=p) ----
  const int krow = tid >> 3;                     // 0..31
  const int kc0  = (tid & 7) * 8;
  const int kh2  = (krow >> 2) & 1;
  const int kfmw = ((krow >> 3) << 2) | (krow & 3);
  const int kkk  = (tid >> 2) & 1;
  const int kfq3 = tid & 3;
  const int oK0  = swz(kh2 * 2 + kkk, kfq3 * 16 + kfmw);   // p adds 2048 elems
  const bf16_t* pKs = kh + (long)(kvbase + krow) * HD + kc0;

  const int vd0  = tid >> 4;                     // 0..15
  const int vc0  = (tid & 15) * 8;
  const int vu   = vc0 >> 5;
  const int vslot = ((vc0 >> 3) & 3) * 16 + vd0;
  int oV[4];
  #pragma unroll
  for (int p = 0; p < 4; p++) oV[p] = swz(vu * 4 + p, vslot);
  const bf16_t* pVs = vth + (long)vd0 * SEQ + kvbase + vc0;

  // prologue: tile 0 -> regs
  bf16x8 rK[4], rV[4];
  #pragma unroll
  for (int p = 0; p < 4; p++) {
    rK[p] = *(const bf16x8*)(pKs + p * 32 * HD);
    rV[p] = *(const bf16x8*)(pVs + p * 16 * SEQ);
  }
  pKs += KVT * HD; pVs += KVT;

  f32x4 oA[4] = {}, oB[4] = {};
  f32x4 oLA = {}, oLB = {};
  constexpr int NIT = (SEQ / 2) / KVT;

  for (int it = 0; it < NIT; it++) {
    __syncthreads();                 // all waves done reading previous tile
    #pragma unroll
    for (int p = 0; p < 4; p++) {    // tile it: regs -> LDS (vmcnt waits here)
      *(bf16x8*)&sK[oK0 + p * 2048] = rK[p];
      *(bf16x8*)&sV[oV[p]]          = rV[p];
    }
    if (it + 1 < NIT) {              // issue tile it+1 loads; land during compute
      #pragma unroll
      for (int p = 0; p < 4; p++) {
        rK[p] = *(const bf16x8*)(pKs + p * 32 * HD);
        rV[p] = *(const bf16x8*)(pVs + p * 16 * SEQ);
      }
      pKs += KVT * HD; pVs += KVT;
    }
    __syncthreads();                 // tile it visible

    #pragma unroll
    for (int u = 0; u < 4; u++) {
      f32x4 stA[2], stB[2];
      #pragma unroll
      for (int h2 = 0; h2 < 2; h2++) {
        bf16x8 aK0 = *(const bf16x8*)&sK[swz((u * 2 + h2) * 2 + 0, lane)];
        bf16x8 aK1 = *(const bf16x8*)&sK[swz((u * 2 + h2) * 2 + 1, lane)];
        f32x4 z0 = {};
        z0 = __builtin_amdgcn_mfma_f32_16x16x32_bf16(aK0, bQ[0][0], z0, 0, 0, 0);
        stA[h2] = __builtin_amdgcn_mfma_f32_16x16x32_bf16(aK1, bQ[0][1], z0, 0, 0, 0);
        f32x4 z1 = {};
        z1 = __builtin_amdgcn_mfma_f32_16x16x32_bf16(aK0, bQ[1][0], z1, 0, 0, 0);
        stB[h2] = __builtin_amdgcn_mfma_f32_16x16x32_bf16(aK1, bQ[1][1], z1, 0, 0, 0);
      }
      bf16x8 pA, pB;
      #pragma unroll
      for (int h2 = 0; h2 < 2; h2++)
        #pragma unroll
        for (int r = 0; r < 4; r++) {
          pA[h2 * 4 + r] = (bf16_t)__builtin_amdgcn_exp2f(stA[h2][r]);
          pB[h2 * 4 + r] = (bf16_t)__builtin_amdgcn_exp2f(stB[h2][r]);
        }
      // row sums on the matrix pipe
      oLA = __builtin_amdgcn_mfma_f32_16x16x32_bf16(pA, ones, oLA, 0, 0, 0);
      oLB = __builtin_amdgcn_mfma_f32_16x16x32_bf16(pB, ones, oLB, 0, 0, 0);
      #pragma unroll
      for (int jd = 0; jd < 4; jd++) {
        bf16x8 bV = *(const bf16x8*)&sV[swz(u * 4 + jd, lane)];
        oA[jd] = __builtin_amdgcn_mfma_f32_16x16x32_bf16(pA, bV, oA[jd], 0, 0, 0);
        oB[jd] = __builtin_amdgcn_mfma_f32_16x16x32_bf16(pB, bV, oB[jd], 0, 0, 0);
      }
    }
  }

  // oLA/oLB: D[q][c] with all 16 cols equal; lane fm==0 holds q = fq*4+r
  if (fm == 0) {
    #pragma unroll
    for (int r = 0; r < 4; r++) {
      lp[(long)bh * SEQ + qw0 + fq * 4 + r]      = oLA[r];
      lp[(long)bh * SEQ + qw0 + 16 + fq * 4 + r] = oLB[r];
    }
  }

  #pragma unroll
  for (int r = 0; r < 4; r++) {
    const long rowA = ((long)b * SEQ + qw0 + fq * 4 + r) * DIM + h * HD;
    const long rowB = rowA + 16L * DIM;
    #pragma unroll
    for (int jd = 0; jd < 4; jd++) {
      Op[rowA + jd * 16 + fm] = (bf16_t)oA[jd][r];
      Op[rowB + jd * 16 + fm] = (bf16_t)oB[jd][r];
    }
  }
}

// ------------------------------------------------------------------
// ws layout — 65 MB (unchanged):
// ------------------------------------------------------------------
extern "C" void kernel_launch(void* const* d_in, const int* in_sizes, int n_in,
                              void* d_out, int out_size, void* d_ws, size_t ws_size,
                              hipStream_t stream) {
  (void)in_sizes; (void)n_in; (void)out_size; (void)ws_size;
  const float* x      = (const float*)d_in[0];
  const float* wq     = (const float*)d_in[2];
  const float* wk     = (const float*)d_in[3];
  const float* wv     = (const float*)d_in[4];
  const float* wo     = (const float*)d_in[5];
  const float* w_up   = (const float*)d_in[6];
  const float* b_up   = (const float*)d_in[7];
  const float* w_down = (const float*)d_in[8];
  const float* b_down = (const float*)d_in[9];
  const float* ln1a   = (const float*)d_in[10];
  const float* ln1b   = (const float*)d_in[11];
  const float* ln2a   = (const float*)d_in[12];
  const float* ln2b   = (const float*)d_in[13];

  char* ws = (char*)d_ws;
  const size_t MB = 1ull << 20;
  const size_t KB = 1ull << 10;
  float*  l0     = (float*)(ws);              // 256 KB
  float*  l1     = (float*)(ws + 256 * KB);   // 256 KB
  bf16_t* wqkvT  = (bf16_t*)(ws + 512 * KB);  // 6 MB
  bf16_t* woT    = (bf16_t*)(ws + 512 * KB + 6 * MB);  // 2 MB
  bf16_t* h      = (bf16_t*)(ws + 9 * MB);
  bf16_t* O0     = (bf16_t*)(ws + 9 * MB);
  bf16_t* attn   = (bf16_t*)(ws + 9 * MB);
  bf16_t* qkv    = (bf16_t*)(ws + 17 * MB);
  bf16_t* qd     = (bf16_t*)(ws + 17 * MB);
  bf16_t* kd     = (bf16_t*)(ws + 25 * MB);
  bf16_t* vtd    = (bf16_t*)(ws + 33 * MB);
  bf16_t* O1     = (bf16_t*)(ws + 41 * MB);
  bf16_t* p0_wo  = (bf16_t*)(ws + 17 * MB);
  bf16_t* p1_wo  = (bf16_t*)(ws + 25 * MB);
  bf16_t* x1b    = (bf16_t*)(ws + 41 * MB);
  bf16_t* h2     = (bf16_t*)(ws);
  bf16_t* wdownT = (bf16_t*)(ws + 49 * MB);
  bf16_t* wupT   = (bf16_t*)(ws + 57 * MB);
  bf16_t* ff1    = (bf16_t*)(ws + 9 * MB);
  bf16_t* p0_fd  = (bf16_t*)(ws);
  bf16_t* p1_fd  = (bf16_t*)(ws + 57 * MB);
  float*  outp   = (float*)d_out;

  const dim3 T(256);
  TP tp{wq, wk, wv, wo, w_up, w_down, wqkvT, wupT, wdownT};
  transpose_all<<<dim3(12288), T, 0, stream>>>(tp);

  layernorm_k<<<dim3(4096), T, 0, stream>>>(x, ln1a, ln1b, h);
  gemm_bt<EPI_QKV, 128><<<dim3(24, 32), T, 0, stream>>>(h, DIM, wqkvT, DIM, qkv, vtd,
                                                        nullptr, NTOK, 3072, DIM);
  flash_attn<<<dim3(512, 2), T, 0, stream>>>(qd, kd, vtd, O0, O1, l0, l1);
  combine_att<<<dim3(NTOK * DIM / 1024), T, 0, stream>>>(O1, l0, l1, attn);
  gemm_bt<EPI_PART, 64><<<dim3(16, 32, 2), T, 0, stream>>>(attn, DIM, woT, DIM, p0_wo, p1_wo,
                                                           nullptr, NTOK, DIM, DIM / 2);
  reduce_wo_ln<<<dim3(4096), T, 0, stream>>>(x, p0_wo, p1_wo, ln2a, ln2b, x1b, h2);
  gemm_bt<EPI_BIAS_RELU, 128><<<dim3(32, 32), T, 0, stream>>>(h2, DIM, wupT, DIM, ff1, nullptr,
                                                              b_up, NTOK, DFF, DIM);
  gemm_bt<EPI_PART, 64><<<dim3(16, 32, 2), T, 0, stream>>>(ff1, DFF, wdownT, DFF, p0_fd, p1_fd,
                                                           nullptr, NTOK, DIM, DFF / 2);
  reduce_fd<<<dim3(NTOK * DIM / 1024), T, 0, stream>>>(x1b, b_down, p0_fd, p1_fd, outp);
}

// Round 13
// 367.316 us; speedup vs baseline: 1.2724x; 1.0026x over previous
//
#include <hip/hip_runtime.h>
#include <hip/hip_bf16.h>

typedef __bf16 bf16_t;
typedef __bf16 bf16x8 __attribute__((ext_vector_type(8)));
typedef __bf16 bf16x4 __attribute__((ext_vector_type(4)));
typedef float  f32x4  __attribute__((ext_vector_type(4)));

#define DIM   1024
#define NHEAD 16
#define HD    64
#define DFF   4096
#define SEQ   2048
#define NTOK  4096   // B*S

// lgkm-only barrier: drains LDS ops (cross-wave visibility) but leaves
// global->VGPR prefetch loads in flight across the barrier.
__device__ __forceinline__ void lgkm_barrier() {
  asm volatile("s_waitcnt lgkmcnt(0)\n\ts_barrier" ::: "memory");
}

// ------------------------------------------------------------------
// ALL six weight transposes in one launch. 12288 32x32-tile blocks.
// ------------------------------------------------------------------
struct TP {
  const float *wq, *wk, *wv, *wo, *wup, *wdown;
  bf16_t *wqkvT, *wupT, *wdownT;
};

__global__ __launch_bounds__(256)
void transpose_all(TP tp) {
  __shared__ bf16_t tile[32][33];
  const int id = blockIdx.x;
  const float* src; bf16_t* dst; int M, N, bx, by;
  if (id < 4096) {
    const int w = id >> 10, t = id & 1023;
    src = (w == 0) ? tp.wq : (w == 1) ? tp.wk : (w == 2) ? tp.wv : tp.wo;
    dst = tp.wqkvT + (long)w * DIM * DIM;
    M = DIM; N = DIM; bx = (t & 31) * 32; by = (t >> 5) * 32;
  } else if (id < 8192) {
    const int t = id - 4096;
    src = tp.wup; dst = tp.wupT; M = DIM; N = DFF;
    bx = (t & 127) * 32; by = (t >> 7) * 32;
  } else {
    const int t = id - 8192;
    src = tp.wdown; dst = tp.wdownT; M = DFF; N = DIM;
    bx = (t & 31) * 32; by = (t >> 5) * 32;
  }
  const int tt = threadIdx.x;
  const int r = tt >> 3, c4 = (tt & 7) * 4;
  f32x4 v = *(const f32x4*)&src[(long)(by + r) * N + bx + c4];
  tile[r][c4 + 0] = (bf16_t)v[0]; tile[r][c4 + 1] = (bf16_t)v[1];
  tile[r][c4 + 2] = (bf16_t)v[2]; tile[r][c4 + 3] = (bf16_t)v[3];
  __syncthreads();
  bf16x4 w4;
  w4[0] = tile[c4 + 0][r]; w4[1] = tile[c4 + 1][r];
  w4[2] = tile[c4 + 2][r]; w4[3] = tile[c4 + 3][r];
  *(bf16x4*)&dst[(long)(bx + r) * M + by + c4] = w4;
}

// ------------------------------------------------------------------
// LayerNorm (fp32 in, bf16 out) — ddof=1 std, /(sigma+eps).
// ------------------------------------------------------------------
__global__ __launch_bounds__(256)
void layernorm_k(const float* __restrict__ x, const float* __restrict__ a,
                 const float* __restrict__ b, bf16_t* __restrict__ out) {
  const int row = blockIdx.x;
  const int t   = threadIdx.x;
  const float* xr = x + (long)row * DIM;
  f32x4 v = *(const f32x4*)&xr[t * 4];
  float s1 = v[0] + v[1] + v[2] + v[3];
  float s2 = v[0]*v[0] + v[1]*v[1] + v[2]*v[2] + v[3]*v[3];
  #pragma unroll
  for (int off = 32; off > 0; off >>= 1) {
    s1 += __shfl_down(s1, off);
    s2 += __shfl_down(s2, off);
  }
  __shared__ float r1[4], r2[4];
  if ((t & 63) == 0) { r1[t >> 6] = s1; r2[t >> 6] = s2; }
  __syncthreads();
  s1 = r1[0] + r1[1] + r1[2] + r1[3];
  s2 = r2[0] + r2[1] + r2[2] + r2[3];
  const float mu = s1 * (1.0f / DIM);
  float var = (s2 - (float)DIM * mu * mu) * (1.0f / (DIM - 1));
  var = fmaxf(var, 0.0f);
  const float inv = 1.0f / (sqrtf(var) + 1e-6f);
  f32x4 av = *(const f32x4*)&a[t * 4];
  f32x4 bv = *(const f32x4*)&b[t * 4];
  bf16x4 o;
  o[0] = (bf16_t)(av[0] * (v[0] - mu) * inv + bv[0]);
  o[1] = (bf16_t)(av[1] * (v[1] - mu) * inv + bv[1]);
  o[2] = (bf16_t)(av[2] * (v[2] - mu) * inv + bv[2]);
  o[3] = (bf16_t)(av[3] * (v[3] - mu) * inv + bv[3]);
  *(bf16x4*)&out[(long)row * DIM + t * 4] = o;
}

// Fused: x1b = bf16(x + p0 + p1), h2 = LN2(x1b).  One block per row.
__global__ __launch_bounds__(256)
void reduce_wo_ln(const float* __restrict__ x, const bf16_t* __restrict__ p0,
                  const bf16_t* __restrict__ p1, const float* __restrict__ a,
                  const float* __restrict__ b, bf16_t* __restrict__ x1b,
                  bf16_t* __restrict__ h2) {
  const int row = blockIdx.x;
  const int t   = threadIdx.x;
  const long base = (long)row * DIM + t * 4;
  f32x4 v = *(const f32x4*)&x[base];
  bf16x4 pa = *(const bf16x4*)&p0[base];
  bf16x4 pb = *(const bf16x4*)&p1[base];
  bf16x4 xo;
  xo[0] = (bf16_t)(v[0] + (float)pa[0] + (float)pb[0]);
  xo[1] = (bf16_t)(v[1] + (float)pa[1] + (float)pb[1]);
  xo[2] = (bf16_t)(v[2] + (float)pa[2] + (float)pb[2]);
  xo[3] = (bf16_t)(v[3] + (float)pa[3] + (float)pb[3]);
  *(bf16x4*)&x1b[base] = xo;
  const float w0 = (float)xo[0], w1 = (float)xo[1], w2 = (float)xo[2], w3 = (float)xo[3];
  float s1 = w0 + w1 + w2 + w3;
  float s2 = w0*w0 + w1*w1 + w2*w2 + w3*w3;
  #pragma unroll
  for (int off = 32; off > 0; off >>= 1) {
    s1 += __shfl_down(s1, off);
    s2 += __shfl_down(s2, off);
  }
  __shared__ float r1[4], r2[4];
  if ((t & 63) == 0) { r1[t >> 6] = s1; r2[t >> 6] = s2; }
  __syncthreads();
  s1 = r1[0] + r1[1] + r1[2] + r1[3];
  s2 = r2[0] + r2[1] + r2[2] + r2[3];
  const float mu = s1 * (1.0f / DIM);
  float var = (s2 - (float)DIM * mu * mu) * (1.0f / (DIM - 1));
  var = fmaxf(var, 0.0f);
  const float inv = 1.0f / (sqrtf(var) + 1e-6f);
  f32x4 av = *(const f32x4*)&a[t * 4];
  f32x4 bv = *(const f32x4*)&b[t * 4];
  bf16x4 o;
  o[0] = (bf16_t)(av[0] * (w0 - mu) * inv + bv[0]);
  o[1] = (bf16_t)(av[1] * (w1 - mu) * inv + bv[1]);
  o[2] = (bf16_t)(av[2] * (w2 - mu) * inv + bv[2]);
  o[3] = (bf16_t)(av[3] * (w3 - mu) * inv + bv[3]);
  *(bf16x4*)&h2[(long)row * DIM + t * 4] = o;
}

// attn = (O0 + O1) / (l0 + l1)   (split-KV combine; in-place over O0)
__global__ __launch_bounds__(256)
void combine_att(const bf16_t* __restrict__ O1, const float* __restrict__ l0,
                 const float* __restrict__ l1, bf16_t* __restrict__ O0_attn) {
  const long i = ((long)blockIdx.x * 256 + threadIdx.x) * 4;
  const int n = (int)(i & (DIM - 1));
  const long t = i >> 10;
  const int h = n >> 6;
  const long lidx = ((t >> 11) * NHEAD + h) * SEQ + (t & (SEQ - 1));
  const float inv = 1.0f / (l0[lidx] + l1[lidx]);
  bf16x4 a = *(const bf16x4*)&O0_attn[i];
  bf16x4 b = *(const bf16x4*)&O1[i];
  bf16x4 o;
  o[0] = (bf16_t)(((float)a[0] + (float)b[0]) * inv);
  o[1] = (bf16_t)(((float)a[1] + (float)b[1]) * inv);
  o[2] = (bf16_t)(((float)a[2] + (float)b[2]) * inv);
  o[3] = (bf16_t)(((float)a[3] + (float)b[3]) * inv);
  *(bf16x4*)&O0_attn[i] = o;
}

// out = x1b + bias + p0 + p1  (fp32 out)
__global__ __launch_bounds__(256)
void reduce_fd(const bf16_t* __restrict__ x1b, const float* __restrict__ bias,
               const bf16_t* __restrict__ p0, const bf16_t* __restrict__ p1,
               float* __restrict__ out) {
  const long i = ((long)blockIdx.x * 256 + threadIdx.x) * 4;
  const int n = (int)(i & (DIM - 1));
  bf16x4 xv = *(const bf16x4*)&x1b[i];
  f32x4 bv = *(const f32x4*)&bias[n];
  bf16x4 a = *(const bf16x4*)&p0[i];
  bf16x4 b = *(const bf16x4*)&p1[i];
  f32x4 o;
  o[0] = (float)xv[0] + bv[0] + (float)a[0] + (float)b[0];
  o[1] = (float)xv[1] + bv[1] + (float)a[1] + (float)b[1];
  o[2] = (float)xv[2] + bv[2] + (float)a[2] + (float)b[2];
  o[3] = (float)xv[3] + bv[3] + (float)a[3] + (float)b[3];
  *(f32x4*)&out[i] = o;
}

// ------------------------------------------------------------------
// 128xTBN GEMM v3: v2 + LDS row pad 32->40 elems (80B rows = 20-bank
// stride). Round-11 PMC: SQ_LDS_BANK_CONFLICT=6.29M cycles (~16% of the
// FFN-down kernel). With 64B rows, ds_read_b128 fragment reads had lanes
// fm,fm+2,... aliasing one bank-quad = 8-way conflict (2.94x, m136).
// 80B rows: bank(fm)=(20*fm+4*fq)%32, period 8 -> only fm,fm+8 alias =
// 2-way (free). 16B alignment kept (80 and all fq*16 offsets are 16B
// multiples). LDS: TBN=128 40KB (4 blk/CU), TBN=64 30KB (5 blk/CU).
// ------------------------------------------------------------------
enum { EPI_QKV = 1, EPI_BIAS_RELU = 3, EPI_PART = 6 };

#define BM 128
#define BK 32
#define BKP 40   // padded row length (elements)

template <int EPI, int TBN>
__global__ __launch_bounds__(256)
void gemm_bt(const bf16_t* __restrict__ A, int lda,
             const bf16_t* __restrict__ BT, int ldb,
             bf16_t* __restrict__ Cb, bf16_t* __restrict__ Cb2,
             const float* __restrict__ bias,
             int M, int N, int Ks) {
  __shared__ bf16_t sA[2][BM][BKP];
  __shared__ bf16_t sB[2][TBN][BKP];
  const int tid  = threadIdx.x;
  int lin = blockIdx.x + gridDim.x * (blockIdx.y + gridDim.y * blockIdx.z);
  const int by_ = lin % gridDim.y; lin /= gridDim.y;
  const int bx_ = lin % gridDim.x;
  const int bz_ = lin / gridDim.x;
  const int m0   = by_ * BM;
  const int n0   = bx_ * TBN;
  const long koff = (long)bz_ * Ks;
  const int lane = tid & 63, wave = tid >> 6;
  constexpr int MI = (TBN == 128) ? 4 : 2;
  const int wm = (TBN == 128) ? (wave >> 1) * 64 : wave * 32;
  const int wn = (TBN == 128) ? (wave & 1) * 64 : 0;
  const int fm = lane & 15, fq = lane >> 4;

  const int lr = lane >> 2, lc = (lane & 3) * 8;
  const bf16_t* gA0 = &A[(long)(m0 + wave * 32 + lr) * lda + koff + lc];
  const bf16_t* gA1 = gA0 + 16 * (long)lda;
  const int brow = (TBN == 128) ? wave * 32 : wave * 16;
  const bf16_t* gB0 = &BT[(long)(n0 + brow + lr) * ldb + koff + lc];
  const bf16_t* gB1 = gB0 + 16 * (long)ldb;   // used only when TBN==128

  f32x4 acc[MI][4] = {};
  bf16x8 rA0, rA1, rB0, rB1;

  rA0 = *(const bf16x8*)gA0;
  rA1 = *(const bf16x8*)gA1;
  rB0 = *(const bf16x8*)gB0;
  if constexpr (TBN == 128) rB1 = *(const bf16x8*)gB1;
  gA0 += BK; gA1 += BK; gB0 += BK; gB1 += BK;
  *(bf16x8*)&sA[0][wave * 32 + lr][lc]      = rA0;
  *(bf16x8*)&sA[0][wave * 32 + 16 + lr][lc] = rA1;
  *(bf16x8*)&sB[0][brow + lr][lc]           = rB0;
  if constexpr (TBN == 128) *(bf16x8*)&sB[0][wave * 32 + 16 + lr][lc] = rB1;
  if (BK < Ks) {
    rA0 = *(const bf16x8*)gA0;
    rA1 = *(const bf16x8*)gA1;
    rB0 = *(const bf16x8*)gB0;
    if constexpr (TBN == 128) rB1 = *(const bf16x8*)gB1;
    gA0 += BK; gA1 += BK; gB0 += BK; gB1 += BK;
  }
  __syncthreads();

  int p = 0;
  for (int k0 = 0; k0 < Ks; k0 += BK, p ^= 1) {
    if (k0 + BK < Ks) {
      *(bf16x8*)&sA[p ^ 1][wave * 32 + lr][lc]      = rA0;
      *(bf16x8*)&sA[p ^ 1][wave * 32 + 16 + lr][lc] = rA1;
      *(bf16x8*)&sB[p ^ 1][brow + lr][lc]           = rB0;
      if constexpr (TBN == 128) *(bf16x8*)&sB[p ^ 1][wave * 32 + 16 + lr][lc] = rB1;
      if (k0 + 2 * BK < Ks) {
        rA0 = *(const bf16x8*)gA0;
        rA1 = *(const bf16x8*)gA1;
        rB0 = *(const bf16x8*)gB0;
        if constexpr (TBN == 128) rB1 = *(const bf16x8*)gB1;
        gA0 += BK; gA1 += BK; gB0 += BK; gB1 += BK;
      }
    }
    bf16x8 af[MI], bfr[4];
    #pragma unroll
    for (int i = 0; i < MI; i++) af[i]  = *(const bf16x8*)&sA[p][wm + i * 16 + fm][fq * 8];
    #pragma unroll
    for (int j = 0; j < 4; j++)  bfr[j] = *(const bf16x8*)&sB[p][wn + j * 16 + fm][fq * 8];
    #pragma unroll
    for (int i = 0; i < MI; i++)
      #pragma unroll
      for (int j = 0; j < 4; j++)
        acc[i][j] = __builtin_amdgcn_mfma_f32_16x16x32_bf16(af[i], bfr[j], acc[i][j], 0, 0, 0);
    lgkm_barrier();
  }

  #pragma unroll
  for (int i = 0; i < MI; i++) {
    #pragma unroll
    for (int j = 0; j < 4; j++) {
      const int mb = m0 + wm + i * 16 + fq * 4;
      const int n  = n0 + wn + j * 16 + fm;
      #pragma unroll
      for (int r = 0; r < 4; r++) {
        const int m = mb + r;
        float vv = acc[i][j][r];
        if constexpr (EPI == EPI_QKV) {
          const int mat = n >> 10, h_ = (n >> 6) & 15, d_ = n & 63;
          const int b_ = m >> 11, s_ = m & 2047;
          if (mat == 2) {
            Cb2[((long)(b_ * NHEAD + h_) * HD + d_) * SEQ + s_] = (bf16_t)vv;
          } else {
            Cb[(long)mat * (32L * SEQ * HD) + (((long)(b_ * NHEAD + h_)) * SEQ + s_) * HD + d_] = (bf16_t)vv;
          }
        } else if constexpr (EPI == EPI_BIAS_RELU) {
          Cb[(long)m * N + n] = (bf16_t)fmaxf(vv + bias[n], 0.0f);
        } else {  // EPI_PART
          bf16_t* P = bz_ ? Cb2 : Cb;
          P[(long)m * N + n] = (bf16_t)vv;
        }
      }
    }
  }
}

// ------------------------------------------------------------------
// Flash attention v8 (unchanged from round 11: 368 us total, flash
// out of top-5): v6 LDS staging + T14 next-tile register prefetch,
// hoisted staging addresses (p enters maps linearly: u=p / jd=p).
// ------------------------------------------------------------------
#define KVT 128

__device__ __forceinline__ int swz(int grp, int slot) {
  return (grp * 64 + (slot ^ ((slot >> 3) & 7) ^ (grp & 1))) * 8;
}

__global__ __launch_bounds__(256)
void flash_attn(const bf16_t* __restrict__ q, const bf16_t* __restrict__ k,
                const bf16_t* __restrict__ vt,
                bf16_t* __restrict__ O0, bf16_t* __restrict__ O1,
                float* __restrict__ l0, float* __restrict__ l1) {
  __shared__ bf16_t sK[16 * 64 * 8];   // 16 KB
  __shared__ bf16_t sV[16 * 64 * 8];   // 16 KB

  const int tid  = threadIdx.x;
  const int bh   = blockIdx.x & 31, qb = blockIdx.x >> 5;   // XCD-cluster
  const int b    = bh >> 4, h = bh & 15;
  const int lane = tid & 63, wave = tid >> 6;
  const int fm   = lane & 15, fq = lane >> 4;
  const int qw0  = qb * 128 + wave * 32;
  const int kvbase = blockIdx.y * (SEQ / 2);
  bf16_t* Op = blockIdx.y ? O1 : O0;
  float*  lp = blockIdx.y ? l1 : l0;

  const bf16_t* qh  = q  + (long)bh * SEQ * HD;
  const bf16_t* kh  = k  + (long)bh * SEQ * HD;
  const bf16_t* vth = vt + (long)bh * HD * SEQ;

  // Q prescaled by (1/8)*log2(e): scores feed exp2 directly
  bf16x8 bQ[2][2];
  #pragma unroll
  for (int qt = 0; qt < 2; qt++)
    #pragma unroll
    for (int kk = 0; kk < 2; kk++) {
      bf16x8 v = *(const bf16x8*)&qh[(long)(qw0 + qt * 16 + fm) * HD + kk * 32 + fq * 8];
      #pragma unroll
      for (int e = 0; e < 8; e++) v[e] = (bf16_t)((float)v[e] * 0.18033688f);
      bQ[qt][kk] = v;
    }

  // ones-fragment for MFMA row-sums (kv-permutation-invariant)
  bf16x8 ones;
  #pragma unroll
  for (int e = 0; e < 8; e++) ones[e] = (bf16_t)1.0f;

  // ---- loop-invariant staging addresses (v6 maps with u=p, jd=p) ----
  const int krow = tid >> 3;                     // 0..31
  const int kc0  = (tid & 7) * 8;
  const int kh2  = (krow >> 2) & 1;
  const int kfmw = ((krow >> 3) << 2) | (krow & 3);
  const int kkk  = (tid >> 2) & 1;
  const int kfq3 = tid & 3;
  const int oK0  = swz(kh2 * 2 + kkk, kfq3 * 16 + kfmw);   // p adds 2048 elems
  const bf16_t* pKs = kh + (long)(kvbase + krow) * HD + kc0;

  const int vd0  = tid >> 4;                     // 0..15
  const int vc0  = (tid & 15) * 8;
  const int vu   = vc0 >> 5;
  const int vslot = ((vc0 >> 3) & 3) * 16 + vd0;
  int oV[4];
  #pragma unroll
  for (int p = 0; p < 4; p++) oV[p] = swz(vu * 4 + p, vslot);
  const bf16_t* pVs = vth + (long)vd0 * SEQ + kvbase + vc0;

  // prologue: tile 0 -> regs
  bf16x8 rK[4], rV[4];
  #pragma unroll
  for (int p = 0; p < 4; p++) {
    rK[p] = *(const bf16x8*)(pKs + p * 32 * HD);
    rV[p] = *(const bf16x8*)(pVs + p * 16 * SEQ);
  }
  pKs += KVT * HD; pVs += KVT;

  f32x4 oA[4] = {}, oB[4] = {};
  f32x4 oLA = {}, oLB = {};
  constexpr int NIT = (SEQ / 2) / KVT;

  for (int it = 0; it < NIT; it++) {
    __syncthreads();                 // all waves done reading previous tile
    #pragma unroll
    for (int p = 0; p < 4; p++) {    // tile it: regs -> LDS (vmcnt waits here)
      *(bf16x8*)&sK[oK0 + p * 2048] = rK[p];
      *(bf16x8*)&sV[oV[p]]          = rV[p];
    }
    if (it + 1 < NIT) {              // issue tile it+1 loads; land during compute
      #pragma unroll
      for (int p = 0; p < 4; p++) {
        rK[p] = *(const bf16x8*)(pKs + p * 32 * HD);
        rV[p] = *(const bf16x8*)(pVs + p * 16 * SEQ);
      }
      pKs += KVT * HD; pVs += KVT;
    }
    __syncthreads();                 // tile it visible

    #pragma unroll
    for (int u = 0; u < 4; u++) {
      f32x4 stA[2], stB[2];
      #pragma unroll
      for (int h2 = 0; h2 < 2; h2++) {
        bf16x8 aK0 = *(const bf16x8*)&sK[swz((u * 2 + h2) * 2 + 0, lane)];
        bf16x8 aK1 = *(const bf16x8*)&sK[swz((u * 2 + h2) * 2 + 1, lane)];
        f32x4 z0 = {};
        z0 = __builtin_amdgcn_mfma_f32_16x16x32_bf16(aK0, bQ[0][0], z0, 0, 0, 0);
        stA[h2] = __builtin_amdgcn_mfma_f32_16x16x32_bf16(aK1, bQ[0][1], z0, 0, 0, 0);
        f32x4 z1 = {};
        z1 = __builtin_amdgcn_mfma_f32_16x16x32_bf16(aK0, bQ[1][0], z1, 0, 0, 0);
        stB[h2] = __builtin_amdgcn_mfma_f32_16x16x32_bf16(aK1, bQ[1][1], z1, 0, 0, 0);
      }
      bf16x8 pA, pB;
      #pragma unroll
      for (int h2 = 0; h2 < 2; h2++)
        #pragma unroll
        for (int r = 0; r < 4; r++) {
          pA[h2 * 4 + r] = (bf16_t)__builtin_amdgcn_exp2f(stA[h2][r]);
          pB[h2 * 4 + r] = (bf16_t)__builtin_amdgcn_exp2f(stB[h2][r]);
        }
      // row sums on the matrix pipe
      oLA = __builtin_amdgcn_mfma_f32_16x16x32_bf16(pA, ones, oLA, 0, 0, 0);
      oLB = __builtin_amdgcn_mfma_f32_16x16x32_bf16(pB, ones, oLB, 0, 0, 0);
      #pragma unroll
      for (int jd = 0; jd < 4; jd++) {
        bf16x8 bV = *(const bf16x8*)&sV[swz(u * 4 + jd, lane)];
        oA[jd] = __builtin_amdgcn_mfma_f32_16x16x32_bf16(pA, bV, oA[jd], 0, 0, 0);
        oB[jd] = __builtin_amdgcn_mfma_f32_16x16x32_bf16(pB, bV, oB[jd], 0, 0, 0);
      }
    }
  }

  // oLA/oLB: D[q][c] with all 16 cols equal; lane fm==0 holds q = fq*4+r
  if (fm == 0) {
    #pragma unroll
    for (int r = 0; r < 4; r++) {
      lp[(long)bh * SEQ + qw0 + fq * 4 + r]      = oLA[r];
      lp[(long)bh * SEQ + qw0 + 16 + fq * 4 + r] = oLB[r];
    }
  }

  #pragma unroll
  for (int r = 0; r < 4; r++) {
    const long rowA = ((long)b * SEQ + qw0 + fq * 4 + r) * DIM + h * HD;
    const long rowB = rowA + 16L * DIM;
    #pragma unroll
    for (int jd = 0; jd < 4; jd++) {
      Op[rowA + jd * 16 + fm] = (bf16_t)oA[jd][r];
      Op[rowB + jd * 16 + fm] = (bf16_t)oB[jd][r];
    }
  }
}

// ------------------------------------------------------------------
// ws layout — 65 MB (unchanged):
// ------------------------------------------------------------------
extern "C" void kernel_launch(void* const* d_in, const int* in_sizes, int n_in,
                              void* d_out, int out_size, void* d_ws, size_t ws_size,
                              hipStream_t stream) {
  (void)in_sizes; (void)n_in; (void)out_size; (void)ws_size;
  const float* x      = (const float*)d_in[0];
  const float* wq     = (const float*)d_in[2];
  const float* wk     = (const float*)d_in[3];
  const float* wv     = (const float*)d_in[4];
  const float* wo     = (const float*)d_in[5];
  const float* w_up   = (const float*)d_in[6];
  const float* b_up   = (const float*)d_in[7];
  const float* w_down = (const float*)d_in[8];
  const float* b_down = (const float*)d_in[9];
  const float* ln1a   = (const float*)d_in[10];
  const float* ln1b   = (const float*)d_in[11];
  const float* ln2a   = (const float*)d_in[12];
  const float* ln2b   = (const float*)d_in[13];

  char* ws = (char*)d_ws;
  const size_t MB = 1ull << 20;
  const size_t KB = 1ull << 10;
  float*  l0     = (float*)(ws);              // 256 KB
  float*  l1     = (float*)(ws + 256 * KB);   // 256 KB
  bf16_t* wqkvT  = (bf16_t*)(ws + 512 * KB);  // 6 MB
  bf16_t* woT    = (bf16_t*)(ws + 512 * KB + 6 * MB);  // 2 MB
  bf16_t* h      = (bf16_t*)(ws + 9 * MB);
  bf16_t* O0     = (bf16_t*)(ws + 9 * MB);
  bf16_t* attn   = (bf16_t*)(ws + 9 * MB);
  bf16_t* qkv    = (bf16_t*)(ws + 17 * MB);
  bf16_t* qd     = (bf16_t*)(ws + 17 * MB);
  bf16_t* kd     = (bf16_t*)(ws + 25 * MB);
  bf16_t* vtd    = (bf16_t*)(ws + 33 * MB);
  bf16_t* O1     = (bf16_t*)(ws + 41 * MB);
  bf16_t* p0_wo  = (bf16_t*)(ws + 17 * MB);
  bf16_t* p1_wo  = (bf16_t*)(ws + 25 * MB);
  bf16_t* x1b    = (bf16_t*)(ws + 41 * MB);
  bf16_t* h2     = (bf16_t*)(ws);
  bf16_t* wdownT = (bf16_t*)(ws + 49 * MB);
  bf16_t* wupT   = (bf16_t*)(ws + 57 * MB);
  bf16_t* ff1    = (bf16_t*)(ws + 9 * MB);
  bf16_t* p0_fd  = (bf16_t*)(ws);
  bf16_t* p1_fd  = (bf16_t*)(ws + 57 * MB);
  float*  outp   = (float*)d_out;

  const dim3 T(256);
  TP tp{wq, wk, wv, wo, w_up, w_down, wqkvT, wupT, wdownT};
  transpose_all<<<dim3(12288), T, 0, stream>>>(tp);

  layernorm_k<<<dim3(4096), T, 0, stream>>>(x, ln1a, ln1b, h);
  gemm_bt<EPI_QKV, 128><<<dim3(24, 32), T, 0, stream>>>(h, DIM, wqkvT, DIM, qkv, vtd,
                                                        nullptr, NTOK, 3072, DIM);
  flash_attn<<<dim3(512, 2), T, 0, stream>>>(qd, kd, vtd, O0, O1, l0, l1);
  combine_att<<<dim3(NTOK * DIM / 1024), T, 0, stream>>>(O1, l0, l1, attn);
  gemm_bt<EPI_PART, 64><<<dim3(16, 32, 2), T, 0, stream>>>(attn, DIM, woT, DIM, p0_wo, p1_wo,
                                                           nullptr, NTOK, DIM, DIM / 2);
  reduce_wo_ln<<<dim3(4096), T, 0, stream>>>(x, p0_wo, p1_wo, ln2a, ln2b, x1b, h2);
  gemm_bt<EPI_BIAS_RELU, 128><<<dim3(32, 32), T, 0, stream>>>(h2, DIM, wupT, DIM, ff1, nullptr,
                                                              b_up, NTOK, DFF, DIM);
  gemm_bt<EPI_PART, 64><<<dim3(16, 32, 2), T, 0, stream>>>(ff1, DFF, wdownT, DFF, p0_fd, p1_fd,
                                                           nullptr, NTOK, DIM, DFF / 2);
  reduce_fd<<<dim3(NTOK * DIM / 1024), T, 0, stream>>>(x1b, b_down, p0_fd, p1_fd, outp);
}

// Round 14
// 366.564 us; speedup vs baseline: 1.2750x; 1.0021x over previous
//
#include <hip/hip_runtime.h>
#include <hip/hip_bf16.h>

typedef __bf16 bf16_t;
typedef __bf16 bf16x8 __attribute__((ext_vector_type(8)));
typedef __bf16 bf16x4 __attribute__((ext_vector_type(4)));
typedef float  f32x4  __attribute__((ext_vector_type(4)));

#define DIM   1024
#define NHEAD 16
#define HD    64
#define DFF   4096
#define SEQ   2048
#define NTOK  4096   // B*S

// lgkm-only barrier: drains LDS ops (cross-wave visibility) but leaves
// global->VGPR prefetch loads in flight across the barrier.
__device__ __forceinline__ void lgkm_barrier() {
  asm volatile("s_waitcnt lgkmcnt(0)\n\ts_barrier" ::: "memory");
}

// ------------------------------------------------------------------
// ALL six weight transposes in one launch. 12288 32x32-tile blocks.
// ------------------------------------------------------------------
struct TP {
  const float *wq, *wk, *wv, *wo, *wup, *wdown;
  bf16_t *wqkvT, *wupT, *wdownT;
};

__global__ __launch_bounds__(256)
void transpose_all(TP tp) {
  __shared__ bf16_t tile[32][33];
  const int id = blockIdx.x;
  const float* src; bf16_t* dst; int M, N, bx, by;
  if (id < 4096) {
    const int w = id >> 10, t = id & 1023;
    src = (w == 0) ? tp.wq : (w == 1) ? tp.wk : (w == 2) ? tp.wv : tp.wo;
    dst = tp.wqkvT + (long)w * DIM * DIM;
    M = DIM; N = DIM; bx = (t & 31) * 32; by = (t >> 5) * 32;
  } else if (id < 8192) {
    const int t = id - 4096;
    src = tp.wup; dst = tp.wupT; M = DIM; N = DFF;
    bx = (t & 127) * 32; by = (t >> 7) * 32;
  } else {
    const int t = id - 8192;
    src = tp.wdown; dst = tp.wdownT; M = DFF; N = DIM;
    bx = (t & 31) * 32; by = (t >> 5) * 32;
  }
  const int tt = threadIdx.x;
  const int r = tt >> 3, c4 = (tt & 7) * 4;
  f32x4 v = *(const f32x4*)&src[(long)(by + r) * N + bx + c4];
  tile[r][c4 + 0] = (bf16_t)v[0]; tile[r][c4 + 1] = (bf16_t)v[1];
  tile[r][c4 + 2] = (bf16_t)v[2]; tile[r][c4 + 3] = (bf16_t)v[3];
  __syncthreads();
  bf16x4 w4;
  w4[0] = tile[c4 + 0][r]; w4[1] = tile[c4 + 1][r];
  w4[2] = tile[c4 + 2][r]; w4[3] = tile[c4 + 3][r];
  *(bf16x4*)&dst[(long)(bx + r) * M + by + c4] = w4;
}

// ------------------------------------------------------------------
// LayerNorm (fp32 in, bf16 out) — ddof=1 std, /(sigma+eps).
// ------------------------------------------------------------------
__global__ __launch_bounds__(256)
void layernorm_k(const float* __restrict__ x, const float* __restrict__ a,
                 const float* __restrict__ b, bf16_t* __restrict__ out) {
  const int row = blockIdx.x;
  const int t   = threadIdx.x;
  const float* xr = x + (long)row * DIM;
  f32x4 v = *(const f32x4*)&xr[t * 4];
  float s1 = v[0] + v[1] + v[2] + v[3];
  float s2 = v[0]*v[0] + v[1]*v[1] + v[2]*v[2] + v[3]*v[3];
  #pragma unroll
  for (int off = 32; off > 0; off >>= 1) {
    s1 += __shfl_down(s1, off);
    s2 += __shfl_down(s2, off);
  }
  __shared__ float r1[4], r2[4];
  if ((t & 63) == 0) { r1[t >> 6] = s1; r2[t >> 6] = s2; }
  __syncthreads();
  s1 = r1[0] + r1[1] + r1[2] + r1[3];
  s2 = r2[0] + r2[1] + r2[2] + r2[3];
  const float mu = s1 * (1.0f / DIM);
  float var = (s2 - (float)DIM * mu * mu) * (1.0f / (DIM - 1));
  var = fmaxf(var, 0.0f);
  const float inv = 1.0f / (sqrtf(var) + 1e-6f);
  f32x4 av = *(const f32x4*)&a[t * 4];
  f32x4 bv = *(const f32x4*)&b[t * 4];
  bf16x4 o;
  o[0] = (bf16_t)(av[0] * (v[0] - mu) * inv + bv[0]);
  o[1] = (bf16_t)(av[1] * (v[1] - mu) * inv + bv[1]);
  o[2] = (bf16_t)(av[2] * (v[2] - mu) * inv + bv[2]);
  o[3] = (bf16_t)(av[3] * (v[3] - mu) * inv + bv[3]);
  *(bf16x4*)&out[(long)row * DIM + t * 4] = o;
}

// Fused: x1b = bf16(x + p0 + p1), h2 = LN2(x1b).  One block per row.
__global__ __launch_bounds__(256)
void reduce_wo_ln(const float* __restrict__ x, const bf16_t* __restrict__ p0,
                  const bf16_t* __restrict__ p1, const float* __restrict__ a,
                  const float* __restrict__ b, bf16_t* __restrict__ x1b,
                  bf16_t* __restrict__ h2) {
  const int row = blockIdx.x;
  const int t   = threadIdx.x;
  const long base = (long)row * DIM + t * 4;
  f32x4 v = *(const f32x4*)&x[base];
  bf16x4 pa = *(const bf16x4*)&p0[base];
  bf16x4 pb = *(const bf16x4*)&p1[base];
  bf16x4 xo;
  xo[0] = (bf16_t)(v[0] + (float)pa[0] + (float)pb[0]);
  xo[1] = (bf16_t)(v[1] + (float)pa[1] + (float)pb[1]);
  xo[2] = (bf16_t)(v[2] + (float)pa[2] + (float)pb[2]);
  xo[3] = (bf16_t)(v[3] + (float)pa[3] + (float)pb[3]);
  *(bf16x4*)&x1b[base] = xo;
  const float w0 = (float)xo[0], w1 = (float)xo[1], w2 = (float)xo[2], w3 = (float)xo[3];
  float s1 = w0 + w1 + w2 + w3;
  float s2 = w0*w0 + w1*w1 + w2*w2 + w3*w3;
  #pragma unroll
  for (int off = 32; off > 0; off >>= 1) {
    s1 += __shfl_down(s1, off);
    s2 += __shfl_down(s2, off);
  }
  __shared__ float r1[4], r2[4];
  if ((t & 63) == 0) { r1[t >> 6] = s1; r2[t >> 6] = s2; }
  __syncthreads();
  s1 = r1[0] + r1[1] + r1[2] + r1[3];
  s2 = r2[0] + r2[1] + r2[2] + r2[3];
  const float mu = s1 * (1.0f / DIM);
  float var = (s2 - (float)DIM * mu * mu) * (1.0f / (DIM - 1));
  var = fmaxf(var, 0.0f);
  const float inv = 1.0f / (sqrtf(var) + 1e-6f);
  f32x4 av = *(const f32x4*)&a[t * 4];
  f32x4 bv = *(const f32x4*)&b[t * 4];
  bf16x4 o;
  o[0] = (bf16_t)(av[0] * (w0 - mu) * inv + bv[0]);
  o[1] = (bf16_t)(av[1] * (w1 - mu) * inv + bv[1]);
  o[2] = (bf16_t)(av[2] * (w2 - mu) * inv + bv[2]);
  o[3] = (bf16_t)(av[3] * (w3 - mu) * inv + bv[3]);
  *(bf16x4*)&h2[(long)row * DIM + t * 4] = o;
}

// attn = (O0 + O1) / (l0 + l1)   (split-KV combine; in-place over O0)
__global__ __launch_bounds__(256)
void combine_att(const bf16_t* __restrict__ O1, const float* __restrict__ l0,
                 const float* __restrict__ l1, bf16_t* __restrict__ O0_attn) {
  const long i = ((long)blockIdx.x * 256 + threadIdx.x) * 4;
  const int n = (int)(i & (DIM - 1));
  const long t = i >> 10;
  const int h = n >> 6;
  const long lidx = ((t >> 11) * NHEAD + h) * SEQ + (t & (SEQ - 1));
  const float inv = 1.0f / (l0[lidx] + l1[lidx]);
  bf16x4 a = *(const bf16x4*)&O0_attn[i];
  bf16x4 b = *(const bf16x4*)&O1[i];
  bf16x4 o;
  o[0] = (bf16_t)(((float)a[0] + (float)b[0]) * inv);
  o[1] = (bf16_t)(((float)a[1] + (float)b[1]) * inv);
  o[2] = (bf16_t)(((float)a[2] + (float)b[2]) * inv);
  o[3] = (bf16_t)(((float)a[3] + (float)b[3]) * inv);
  *(bf16x4*)&O0_attn[i] = o;
}

// out = x1b + bias + p0 + p1  (fp32 out)
__global__ __launch_bounds__(256)
void reduce_fd(const bf16_t* __restrict__ x1b, const float* __restrict__ bias,
               const bf16_t* __restrict__ p0, const bf16_t* __restrict__ p1,
               float* __restrict__ out) {
  const long i = ((long)blockIdx.x * 256 + threadIdx.x) * 4;
  const int n = (int)(i & (DIM - 1));
  bf16x4 xv = *(const bf16x4*)&x1b[i];
  f32x4 bv = *(const f32x4*)&bias[n];
  bf16x4 a = *(const bf16x4*)&p0[i];
  bf16x4 b = *(const bf16x4*)&p1[i];
  f32x4 o;
  o[0] = (float)xv[0] + bv[0] + (float)a[0] + (float)b[0];
  o[1] = (float)xv[1] + bv[1] + (float)a[1] + (float)b[1];
  o[2] = (float)xv[2] + bv[2] + (float)a[2] + (float)b[2];
  o[3] = (float)xv[3] + bv[3] + (float)a[3] + (float)b[3];
  *(f32x4*)&out[i] = o;
}

// ------------------------------------------------------------------
// 128xTBN GEMM v4: BK=32 (contiguous, conflict-free staging writes
// restored) + 16B-chunk XOR swizzle on the column: chunk' = chunk ^
// ((row>>1)&3). Round-13 postmortem: BKP=40 padding left reads 8-way
// (starts 4*((5fm+fq)%8) cover only 8 quads with 8 lanes each) AND
// broke the formerly-contiguous writes -> conflicts doubled 6.29M->
// 12.58M. The XOR swizzle (16-lane-group model, m201):
//  reads  (row=base+fm, chunk=fq):  even fm -> quads {0,4,8,12} x2,
//         odd fm -> {16,20,24,28} x2  => 2-way, free (m136)
//  writes (row=base+lr, chunk=lane&3): each quad exactly 2 lanes => free
// (row>>1)&3 reduces to (fm>>1)&3 / (lr>>1)&3 at every site (bases are
// multiples of 16), so both swizzled columns are loop-invariant:
// zero extra VALU in the K-loop. XOR offsets {0,16,32,48}B keep 16B
// alignment; same permutation on both sides => bit-identical data.
// ------------------------------------------------------------------
enum { EPI_QKV = 1, EPI_BIAS_RELU = 3, EPI_PART = 6 };

#define BM 128
#define BK 32

template <int EPI, int TBN>
__global__ __launch_bounds__(256)
void gemm_bt(const bf16_t* __restrict__ A, int lda,
             const bf16_t* __restrict__ BT, int ldb,
             bf16_t* __restrict__ Cb, bf16_t* __restrict__ Cb2,
             const float* __restrict__ bias,
             int M, int N, int Ks) {
  __shared__ bf16_t sA[2][BM][BK];
  __shared__ bf16_t sB[2][TBN][BK];
  const int tid  = threadIdx.x;
  int lin = blockIdx.x + gridDim.x * (blockIdx.y + gridDim.y * blockIdx.z);
  const int by_ = lin % gridDim.y; lin /= gridDim.y;
  const int bx_ = lin % gridDim.x;
  const int bz_ = lin / gridDim.x;
  const int m0   = by_ * BM;
  const int n0   = bx_ * TBN;
  const long koff = (long)bz_ * Ks;
  const int lane = tid & 63, wave = tid >> 6;
  constexpr int MI = (TBN == 128) ? 4 : 2;
  const int wm = (TBN == 128) ? (wave >> 1) * 64 : wave * 32;
  const int wn = (TBN == 128) ? (wave & 1) * 64 : 0;
  const int fm = lane & 15, fq = lane >> 4;

  const int lr = lane >> 2, lc = (lane & 3) * 8;
  // swizzled columns (loop-invariant): chunk' = chunk ^ ((row>>1)&3)
  const int lcs = lc ^ (((lr >> 1) & 3) << 3);       // staging writes
  const int fqs = (fq * 8) ^ (((fm >> 1) & 3) << 3); // fragment reads

  const bf16_t* gA0 = &A[(long)(m0 + wave * 32 + lr) * lda + koff + lc];
  const bf16_t* gA1 = gA0 + 16 * (long)lda;
  const int brow = (TBN == 128) ? wave * 32 : wave * 16;
  const bf16_t* gB0 = &BT[(long)(n0 + brow + lr) * ldb + koff + lc];
  const bf16_t* gB1 = gB0 + 16 * (long)ldb;   // used only when TBN==128

  f32x4 acc[MI][4] = {};
  bf16x8 rA0, rA1, rB0, rB1;

  rA0 = *(const bf16x8*)gA0;
  rA1 = *(const bf16x8*)gA1;
  rB0 = *(const bf16x8*)gB0;
  if constexpr (TBN == 128) rB1 = *(const bf16x8*)gB1;
  gA0 += BK; gA1 += BK; gB0 += BK; gB1 += BK;
  *(bf16x8*)&sA[0][wave * 32 + lr][lcs]      = rA0;
  *(bf16x8*)&sA[0][wave * 32 + 16 + lr][lcs] = rA1;
  *(bf16x8*)&sB[0][brow + lr][lcs]           = rB0;
  if constexpr (TBN == 128) *(bf16x8*)&sB[0][wave * 32 + 16 + lr][lcs] = rB1;
  if (BK < Ks) {
    rA0 = *(const bf16x8*)gA0;
    rA1 = *(const bf16x8*)gA1;
    rB0 = *(const bf16x8*)gB0;
    if constexpr (TBN == 128) rB1 = *(const bf16x8*)gB1;
    gA0 += BK; gA1 += BK; gB0 += BK; gB1 += BK;
  }
  __syncthreads();

  int p = 0;
  for (int k0 = 0; k0 < Ks; k0 += BK, p ^= 1) {
    if (k0 + BK < Ks) {
      *(bf16x8*)&sA[p ^ 1][wave * 32 + lr][lcs]      = rA0;
      *(bf16x8*)&sA[p ^ 1][wave * 32 + 16 + lr][lcs] = rA1;
      *(bf16x8*)&sB[p ^ 1][brow + lr][lcs]           = rB0;
      if constexpr (TBN == 128) *(bf16x8*)&sB[p ^ 1][wave * 32 + 16 + lr][lcs] = rB1;
      if (k0 + 2 * BK < Ks) {
        rA0 = *(const bf16x8*)gA0;
        rA1 = *(const bf16x8*)gA1;
        rB0 = *(const bf16x8*)gB0;
        if constexpr (TBN == 128) rB1 = *(const bf16x8*)gB1;
        gA0 += BK; gA1 += BK; gB0 += BK; gB1 += BK;
      }
    }
    bf16x8 af[MI], bfr[4];
    #pragma unroll
    for (int i = 0; i < MI; i++) af[i]  = *(const bf16x8*)&sA[p][wm + i * 16 + fm][fqs];
    #pragma unroll
    for (int j = 0; j < 4; j++)  bfr[j] = *(const bf16x8*)&sB[p][wn + j * 16 + fm][fqs];
    #pragma unroll
    for (int i = 0; i < MI; i++)
      #pragma unroll
      for (int j = 0; j < 4; j++)
        acc[i][j] = __builtin_amdgcn_mfma_f32_16x16x32_bf16(af[i], bfr[j], acc[i][j], 0, 0, 0);
    lgkm_barrier();
  }

  #pragma unroll
  for (int i = 0; i < MI; i++) {
    #pragma unroll
    for (int j = 0; j < 4; j++) {
      const int mb = m0 + wm + i * 16 + fq * 4;
      const int n  = n0 + wn + j * 16 + fm;
      #pragma unroll
      for (int r = 0; r < 4; r++) {
        const int m = mb + r;
        float vv = acc[i][j][r];
        if constexpr (EPI == EPI_QKV) {
          const int mat = n >> 10, h_ = (n >> 6) & 15, d_ = n & 63;
          const int b_ = m >> 11, s_ = m & 2047;
          if (mat == 2) {
            Cb2[((long)(b_ * NHEAD + h_) * HD + d_) * SEQ + s_] = (bf16_t)vv;
          } else {
            Cb[(long)mat * (32L * SEQ * HD) + (((long)(b_ * NHEAD + h_)) * SEQ + s_) * HD + d_] = (bf16_t)vv;
          }
        } else if constexpr (EPI == EPI_BIAS_RELU) {
          Cb[(long)m * N + n] = (bf16_t)fmaxf(vv + bias[n], 0.0f);
        } else {  // EPI_PART
          bf16_t* P = bz_ ? Cb2 : Cb;
          P[(long)m * N + n] = (bf16_t)vv;
        }
      }
    }
  }
}

// ------------------------------------------------------------------
// Flash attention v8 (unchanged from round 11: 368 us total, flash
// out of top-5): v6 LDS staging + T14 next-tile register prefetch,
// hoisted staging addresses (p enters maps linearly: u=p / jd=p).
// ------------------------------------------------------------------
#define KVT 128

__device__ __forceinline__ int swz(int grp, int slot) {
  return (grp * 64 + (slot ^ ((slot >> 3) & 7) ^ (grp & 1))) * 8;
}

__global__ __launch_bounds__(256)
void flash_attn(const bf16_t* __restrict__ q, const bf16_t* __restrict__ k,
                const bf16_t* __restrict__ vt,
                bf16_t* __restrict__ O0, bf16_t* __restrict__ O1,
                float* __restrict__ l0, float* __restrict__ l1) {
  __shared__ bf16_t sK[16 * 64 * 8];   // 16 KB
  __shared__ bf16_t sV[16 * 64 * 8];   // 16 KB

  const int tid  = threadIdx.x;
  const int bh   = blockIdx.x & 31, qb = blockIdx.x >> 5;   // XCD-cluster
  const int b    = bh >> 4, h = bh & 15;
  const int lane = tid & 63, wave = tid >> 6;
  const int fm   = lane & 15, fq = lane >> 4;
  const int qw0  = qb * 128 + wave * 32;
  const int kvbase = blockIdx.y * (SEQ / 2);
  bf16_t* Op = blockIdx.y ? O1 : O0;
  float*  lp = blockIdx.y ? l1 : l0;

  const bf16_t* qh  = q  + (long)bh * SEQ * HD;
  const bf16_t* kh  = k  + (long)bh * SEQ * HD;
  const bf16_t* vth = vt + (long)bh * HD * SEQ;

  // Q prescaled by (1/8)*log2(e): scores feed exp2 directly
  bf16x8 bQ[2][2];
  #pragma unroll
  for (int qt = 0; qt < 2; qt++)
    #pragma unroll
    for (int kk = 0; kk < 2; kk++) {
      bf16x8 v = *(const bf16x8*)&qh[(long)(qw0 + qt * 16 + fm) * HD + kk * 32 + fq * 8];
      #pragma unroll
      for (int e = 0; e < 8; e++) v[e] = (bf16_t)((float)v[e] * 0.18033688f);
      bQ[qt][kk] = v;
    }

  // ones-fragment for MFMA row-sums (kv-permutation-invariant)
  bf16x8 ones;
  #pragma unroll
  for (int e = 0; e < 8; e++) ones[e] = (bf16_t)1.0f;

  // ---- loop-invariant staging addresses (v6 maps with u=p, jd=p) ----
  const int krow = tid >> 3;                     // 0..31
  const int kc0  = (tid & 7) * 8;
  const int kh2  = (krow >> 2) & 1;
  const int kfmw = ((krow >> 3) << 2) | (krow & 3);
  const int kkk  = (tid >> 2) & 1;
  const int kfq3 = tid & 3;
  const int oK0  = swz(kh2 * 2 + kkk, kfq3 * 16 + kfmw);   // p adds 2048 elems
  const bf16_t* pKs = kh + (long)(kvbase + krow) * HD + kc0;

  const int vd0  = tid >> 4;                     // 0..15
  const int vc0  = (tid & 15) * 8;
  const int vu   = vc0 >> 5;
  const int vslot = ((vc0 >> 3) & 3) * 16 + vd0;
  int oV[4];
  #pragma unroll
  for (int p = 0; p < 4; p++) oV[p] = swz(vu * 4 + p, vslot);
  const bf16_t* pVs = vth + (long)vd0 * SEQ + kvbase + vc0;

  // prologue: tile 0 -> regs
  bf16x8 rK[4], rV[4];
  #pragma unroll
  for (int p = 0; p < 4; p++) {
    rK[p] = *(const bf16x8*)(pKs + p * 32 * HD);
    rV[p] = *(const bf16x8*)(pVs + p * 16 * SEQ);
  }
  pKs += KVT * HD; pVs += KVT;

  f32x4 oA[4] = {}, oB[4] = {};
  f32x4 oLA = {}, oLB = {};
  constexpr int NIT = (SEQ / 2) / KVT;

  for (int it = 0; it < NIT; it++) {
    __syncthreads();                 // all waves done reading previous tile
    #pragma unroll
    for (int p = 0; p < 4; p++) {    // tile it: regs -> LDS (vmcnt waits here)
      *(bf16x8*)&sK[oK0 + p * 2048] = rK[p];
      *(bf16x8*)&sV[oV[p]]          = rV[p];
    }
    if (it + 1 < NIT) {              // issue tile it+1 loads; land during compute
      #pragma unroll
      for (int p = 0; p < 4; p++) {
        rK[p] = *(const bf16x8*)(pKs + p * 32 * HD);
        rV[p] = *(const bf16x8*)(pVs + p * 16 * SEQ);
      }
      pKs += KVT * HD; pVs += KVT;
    }
    __syncthreads();                 // tile it visible

    #pragma unroll
    for (int u = 0; u < 4; u++) {
      f32x4 stA[2], stB[2];
      #pragma unroll
      for (int h2 = 0; h2 < 2; h2++) {
        bf16x8 aK0 = *(const bf16x8*)&sK[swz((u * 2 + h2) * 2 + 0, lane)];
        bf16x8 aK1 = *(const bf16x8*)&sK[swz((u * 2 + h2) * 2 + 1, lane)];
        f32x4 z0 = {};
        z0 = __builtin_amdgcn_mfma_f32_16x16x32_bf16(aK0, bQ[0][0], z0, 0, 0, 0);
        stA[h2] = __builtin_amdgcn_mfma_f32_16x16x32_bf16(aK1, bQ[0][1], z0, 0, 0, 0);
        f32x4 z1 = {};
        z1 = __builtin_amdgcn_mfma_f32_16x16x32_bf16(aK0, bQ[1][0], z1, 0, 0, 0);
        stB[h2] = __builtin_amdgcn_mfma_f32_16x16x32_bf16(aK1, bQ[1][1], z1, 0, 0, 0);
      }
      bf16x8 pA, pB;
      #pragma unroll
      for (int h2 = 0; h2 < 2; h2++)
        #pragma unroll
        for (int r = 0; r < 4; r++) {
          pA[h2 * 4 + r] = (bf16_t)__builtin_amdgcn_exp2f(stA[h2][r]);
          pB[h2 * 4 + r] = (bf16_t)__builtin_amdgcn_exp2f(stB[h2][r]);
        }
      // row sums on the matrix pipe
      oLA = __builtin_amdgcn_mfma_f32_16x16x32_bf16(pA, ones, oLA, 0, 0, 0);
      oLB = __builtin_amdgcn_mfma_f32_16x16x32_bf16(pB, ones, oLB, 0, 0, 0);
      #pragma unroll
      for (int jd = 0; jd < 4; jd++) {
        bf16x8 bV = *(const bf16x8*)&sV[swz(u * 4 + jd, lane)];
        oA[jd] = __builtin_amdgcn_mfma_f32_16x16x32_bf16(pA, bV, oA[jd], 0, 0, 0);
        oB[jd] = __builtin_amdgcn_mfma_f32_16x16x32_bf16(pB, bV, oB[jd], 0, 0, 0);
      }
    }
  }

  // oLA/oLB: D[q][c] with all 16 cols equal; lane fm==0 holds q = fq*4+r
  if (fm == 0) {
    #pragma unroll
    for (int r = 0; r < 4; r++) {
      lp[(long)bh * SEQ + qw0 + fq * 4 + r]      = oLA[r];
      lp[(long)bh * SEQ + qw0 + 16 + fq * 4 + r] = oLB[r];
    }
  }

  #pragma unroll
  for (int r = 0; r < 4; r++) {
    const long rowA = ((long)b * SEQ + qw0 + fq * 4 + r) * DIM + h * HD;
    const long rowB = rowA + 16L * DIM;
    #pragma unroll
    for (int jd = 0; jd < 4; jd++) {
      Op[rowA + jd * 16 + fm] = (bf16_t)oA[jd][r];
      Op[rowB + jd * 16 + fm] = (bf16_t)oB[jd][r];
    }
  }
}

// ------------------------------------------------------------------
// ws layout — 65 MB (unchanged):
// ------------------------------------------------------------------
extern "C" void kernel_launch(void* const* d_in, const int* in_sizes, int n_in,
                              void* d_out, int out_size, void* d_ws, size_t ws_size,
                              hipStream_t stream) {
  (void)in_sizes; (void)n_in; (void)out_size; (void)ws_size;
  const float* x      = (const float*)d_in[0];
  const float* wq     = (const float*)d_in[2];
  const float* wk     = (const float*)d_in[3];
  const float* wv     = (const float*)d_in[4];
  const float* wo     = (const float*)d_in[5];
  const float* w_up   = (const float*)d_in[6];
  const float* b_up   = (const float*)d_in[7];
  const float* w_down = (const float*)d_in[8];
  const float* b_down = (const float*)d_in[9];
  const float* ln1a   = (const float*)d_in[10];
  const float* ln1b   = (const float*)d_in[11];
  const float* ln2a   = (const float*)d_in[12];
  const float* ln2b   = (const float*)d_in[13];

  char* ws = (char*)d_ws;
  const size_t MB = 1ull << 20;
  const size_t KB = 1ull << 10;
  float*  l0     = (float*)(ws);              // 256 KB
  float*  l1     = (float*)(ws + 256 * KB);   // 256 KB
  bf16_t* wqkvT  = (bf16_t*)(ws + 512 * KB);  // 6 MB
  bf16_t* woT    = (bf16_t*)(ws + 512 * KB + 6 * MB);  // 2 MB
  bf16_t* h      = (bf16_t*)(ws + 9 * MB);
  bf16_t* O0     = (bf16_t*)(ws + 9 * MB);
  bf16_t* attn   = (bf16_t*)(ws + 9 * MB);
  bf16_t* qkv    = (bf16_t*)(ws + 17 * MB);
  bf16_t* qd     = (bf16_t*)(ws + 17 * MB);
  bf16_t* kd     = (bf16_t*)(ws + 25 * MB);
  bf16_t* vtd    = (bf16_t*)(ws + 33 * MB);
  bf16_t* O1     = (bf16_t*)(ws + 41 * MB);
  bf16_t* p0_wo  = (bf16_t*)(ws + 17 * MB);
  bf16_t* p1_wo  = (bf16_t*)(ws + 25 * MB);
  bf16_t* x1b    = (bf16_t*)(ws + 41 * MB);
  bf16_t* h2     = (bf16_t*)(ws);
  bf16_t* wdownT = (bf16_t*)(ws + 49 * MB);
  bf16_t* wupT   = (bf16_t*)(ws + 57 * MB);
  bf16_t* ff1    = (bf16_t*)(ws + 9 * MB);
  bf16_t* p0_fd  = (bf16_t*)(ws);
  bf16_t* p1_fd  = (bf16_t*)(ws + 57 * MB);
  float*  outp   = (float*)d_out;

  const dim3 T(256);
  TP tp{wq, wk, wv, wo, w_up, w_down, wqkvT, wupT, wdownT};
  transpose_all<<<dim3(12288), T, 0, stream>>>(tp);

  layernorm_k<<<dim3(4096), T, 0, stream>>>(x, ln1a, ln1b, h);
  gemm_bt<EPI_QKV, 128><<<dim3(24, 32), T, 0, stream>>>(h, DIM, wqkvT, DIM, qkv, vtd,
                                                        nullptr, NTOK, 3072, DIM);
  flash_attn<<<dim3(512, 2), T, 0, stream>>>(qd, kd, vtd, O0, O1, l0, l1);
  combine_att<<<dim3(NTOK * DIM / 1024), T, 0, stream>>>(O1, l0, l1, attn);
  gemm_bt<EPI_PART, 64><<<dim3(16, 32, 2), T, 0, stream>>>(attn, DIM, woT, DIM, p0_wo, p1_wo,
                                                           nullptr, NTOK, DIM, DIM / 2);
  reduce_wo_ln<<<dim3(4096), T, 0, stream>>>(x, p0_wo, p1_wo, ln2a, ln2b, x1b, h2);
  gemm_bt<EPI_BIAS_RELU, 128><<<dim3(32, 32), T, 0, stream>>>(h2, DIM, wupT, DIM, ff1, nullptr,
                                                              b_up, NTOK, DFF, DIM);
  gemm_bt<EPI_PART, 64><<<dim3(16, 32, 2), T, 0, stream>>>(ff1, DFF, wdownT, DFF, p0_fd, p1_fd,
                                                           nullptr, NTOK, DIM, DFF / 2);
  reduce_fd<<<dim3(NTOK * DIM / 1024), T, 0, stream>>>(x1b, b_down, p0_fd, p1_fd, outp);
}

// Round 18
// 363.747 us; speedup vs baseline: 1.2849x; 1.0077x over previous
//
#include <hip/hip_runtime.h>
#include <hip/hip_bf16.h>

typedef __bf16 bf16_t;
typedef __bf16 bf16x8 __attribute__((ext_vector_type(8)));
typedef __bf16 bf16x4 __attribute__((ext_vector_type(4)));
typedef float  f32x4  __attribute__((ext_vector_type(4)));

#define DIM   1024
#define NHEAD 16
#define HD    64
#define DFF   4096
#define SEQ   2048
#define NTOK  4096   // B*S

// async global->LDS, 16B per lane. HW writes LDS at wave-uniform base +
// lane*16; the global source address is per-lane.
__device__ __forceinline__ void gl16(const bf16_t* g, bf16_t* l) {
  __builtin_amdgcn_global_load_lds(
      (const __attribute__((address_space(1))) void*)g,
      (__attribute__((address_space(3))) void*)l, 16, 0, 0);
}

// ------------------------------------------------------------------
// ALL six weight transposes in one launch. 12288 32x32-tile blocks.
// ------------------------------------------------------------------
struct TP {
  const float *wq, *wk, *wv, *wo, *wup, *wdown;
  bf16_t *wqkvT, *wupT, *wdownT;
};

__global__ __launch_bounds__(256)
void transpose_all(TP tp) {
  __shared__ bf16_t tile[32][33];
  const int id = blockIdx.x;
  const float* src; bf16_t* dst; int M, N, bx, by;
  if (id < 4096) {
    const int w = id >> 10, t = id & 1023;
    src = (w == 0) ? tp.wq : (w == 1) ? tp.wk : (w == 2) ? tp.wv : tp.wo;
    dst = tp.wqkvT + (long)w * DIM * DIM;
    M = DIM; N = DIM; bx = (t & 31) * 32; by = (t >> 5) * 32;
  } else if (id < 8192) {
    const int t = id - 4096;
    src = tp.wup; dst = tp.wupT; M = DIM; N = DFF;
    bx = (t & 127) * 32; by = (t >> 7) * 32;
  } else {
    const int t = id - 8192;
    src = tp.wdown; dst = tp.wdownT; M = DFF; N = DIM;
    bx = (t & 31) * 32; by = (t >> 5) * 32;
  }
  const int tt = threadIdx.x;
  const int r = tt >> 3, c4 = (tt & 7) * 4;
  f32x4 v = *(const f32x4*)&src[(long)(by + r) * N + bx + c4];
  tile[r][c4 + 0] = (bf16_t)v[0]; tile[r][c4 + 1] = (bf16_t)v[1];
  tile[r][c4 + 2] = (bf16_t)v[2]; tile[r][c4 + 3] = (bf16_t)v[3];
  __syncthreads();
  bf16x4 w4;
  w4[0] = tile[c4 + 0][r]; w4[1] = tile[c4 + 1][r];
  w4[2] = tile[c4 + 2][r]; w4[3] = tile[c4 + 3][r];
  *(bf16x4*)&dst[(long)(bx + r) * M + by + c4] = w4;
}

// ------------------------------------------------------------------
// LayerNorm (fp32 in, bf16 out) — ddof=1 std, /(sigma+eps).
// ------------------------------------------------------------------
__global__ __launch_bounds__(256)
void layernorm_k(const float* __restrict__ x, const float* __restrict__ a,
                 const float* __restrict__ b, bf16_t* __restrict__ out) {
  const int row = blockIdx.x;
  const int t   = threadIdx.x;
  const float* xr = x + (long)row * DIM;
  f32x4 v = *(const f32x4*)&xr[t * 4];
  float s1 = v[0] + v[1] + v[2] + v[3];
  float s2 = v[0]*v[0] + v[1]*v[1] + v[2]*v[2] + v[3]*v[3];
  #pragma unroll
  for (int off = 32; off > 0; off >>= 1) {
    s1 += __shfl_down(s1, off);
    s2 += __shfl_down(s2, off);
  }
  __shared__ float r1[4], r2[4];
  if ((t & 63) == 0) { r1[t >> 6] = s1; r2[t >> 6] = s2; }
  __syncthreads();
  s1 = r1[0] + r1[1] + r1[2] + r1[3];
  s2 = r2[0] + r2[1] + r2[2] + r2[3];
  const float mu = s1 * (1.0f / DIM);
  float var = (s2 - (float)DIM * mu * mu) * (1.0f / (DIM - 1));
  var = fmaxf(var, 0.0f);
  const float inv = 1.0f / (sqrtf(var) + 1e-6f);
  f32x4 av = *(const f32x4*)&a[t * 4];
  f32x4 bv = *(const f32x4*)&b[t * 4];
  bf16x4 o;
  o[0] = (bf16_t)(av[0] * (v[0] - mu) * inv + bv[0]);
  o[1] = (bf16_t)(av[1] * (v[1] - mu) * inv + bv[1]);
  o[2] = (bf16_t)(av[2] * (v[2] - mu) * inv + bv[2]);
  o[3] = (bf16_t)(av[3] * (v[3] - mu) * inv + bv[3]);
  *(bf16x4*)&out[(long)row * DIM + t * 4] = o;
}

// Fused: x1b = bf16(x + p0 + p1), h2 = LN2(x1b).  One block per row.
__global__ __launch_bounds__(256)
void reduce_wo_ln(const float* __restrict__ x, const bf16_t* __restrict__ p0,
                  const bf16_t* __restrict__ p1, const float* __restrict__ a,
                  const float* __restrict__ b, bf16_t* __restrict__ x1b,
                  bf16_t* __restrict__ h2) {
  const int row = blockIdx.x;
  const int t   = threadIdx.x;
  const long base = (long)row * DIM + t * 4;
  f32x4 v = *(const f32x4*)&x[base];
  bf16x4 pa = *(const bf16x4*)&p0[base];
  bf16x4 pb = *(const bf16x4*)&p1[base];
  bf16x4 xo;
  xo[0] = (bf16_t)(v[0] + (float)pa[0] + (float)pb[0]);
  xo[1] = (bf16_t)(v[1] + (float)pa[1] + (float)pb[1]);
  xo[2] = (bf16_t)(v[2] + (float)pa[2] + (float)pb[2]);
  xo[3] = (bf16_t)(v[3] + (float)pa[3] + (float)pb[3]);
  *(bf16x4*)&x1b[base] = xo;
  const float w0 = (float)xo[0], w1 = (float)xo[1], w2 = (float)xo[2], w3 = (float)xo[3];
  float s1 = w0 + w1 + w2 + w3;
  float s2 = w0*w0 + w1*w1 + w2*w2 + w3*w3;
  #pragma unroll
  for (int off = 32; off > 0; off >>= 1) {
    s1 += __shfl_down(s1, off);
    s2 += __shfl_down(s2, off);
  }
  __shared__ float r1[4], r2[4];
  if ((t & 63) == 0) { r1[t >> 6] = s1; r2[t >> 6] = s2; }
  __syncthreads();
  s1 = r1[0] + r1[1] + r1[2] + r1[3];
  s2 = r2[0] + r2[1] + r2[2] + r2[3];
  const float mu = s1 * (1.0f / DIM);
  float var = (s2 - (float)DIM * mu * mu) * (1.0f / (DIM - 1));
  var = fmaxf(var, 0.0f);
  const float inv = 1.0f / (sqrtf(var) + 1e-6f);
  f32x4 av = *(const f32x4*)&a[t * 4];
  f32x4 bv = *(const f32x4*)&b[t * 4];
  bf16x4 o;
  o[0] = (bf16_t)(av[0] * (w0 - mu) * inv + bv[0]);
  o[1] = (bf16_t)(av[1] * (w1 - mu) * inv + bv[1]);
  o[2] = (bf16_t)(av[2] * (w2 - mu) * inv + bv[2]);
  o[3] = (bf16_t)(av[3] * (w3 - mu) * inv + bv[3]);
  *(bf16x4*)&h2[(long)row * DIM + t * 4] = o;
}

// attn = (O0 + O1) / (l0 + l1)   (split-KV combine; in-place over O0)
__global__ __launch_bounds__(256)
void combine_att(const bf16_t* __restrict__ O1, const float* __restrict__ l0,
                 const float* __restrict__ l1, bf16_t* __restrict__ O0_attn) {
  const long i = ((long)blockIdx.x * 256 + threadIdx.x) * 4;
  const int n = (int)(i & (DIM - 1));
  const long t = i >> 10;
  const int h = n >> 6;
  const long lidx = ((t >> 11) * NHEAD + h) * SEQ + (t & (SEQ - 1));
  const float inv = 1.0f / (l0[lidx] + l1[lidx]);
  bf16x4 a = *(const bf16x4*)&O0_attn[i];
  bf16x4 b = *(const bf16x4*)&O1[i];
  bf16x4 o;
  o[0] = (bf16_t)(((float)a[0] + (float)b[0]) * inv);
  o[1] = (bf16_t)(((float)a[1] + (float)b[1]) * inv);
  o[2] = (bf16_t)(((float)a[2] + (float)b[2]) * inv);
  o[3] = (bf16_t)(((float)a[3] + (float)b[3]) * inv);
  *(bf16x4*)&O0_attn[i] = o;
}

// out = x1b + bias + p0 + p1  (fp32 out)
__global__ __launch_bounds__(256)
void reduce_fd(const bf16_t* __restrict__ x1b, const float* __restrict__ bias,
               const bf16_t* __restrict__ p0, const bf16_t* __restrict__ p1,
               float* __restrict__ out) {
  const long i = ((long)blockIdx.x * 256 + threadIdx.x) * 4;
  const int n = (int)(i & (DIM - 1));
  bf16x4 xv = *(const bf16x4*)&x1b[i];
  f32x4 bv = *(const f32x4*)&bias[n];
  bf16x4 a = *(const bf16x4*)&p0[i];
  bf16x4 b = *(const bf16x4*)&p1[i];
  f32x4 o;
  o[0] = (float)xv[0] + bv[0] + (float)a[0] + (float)b[0];
  o[1] = (float)xv[1] + bv[1] + (float)a[1] + (float)b[1];
  o[2] = (float)xv[2] + bv[2] + (float)a[2] + (float)b[2];
  o[3] = (float)xv[3] + bv[3] + (float)a[3] + (float)b[3];
  *(f32x4*)&out[i] = o;
}

// ------------------------------------------------------------------
// 128xTBN GEMM v5: staging via global_load_lds width=16 (m151: 874 vs
// 646 TF against reg-staging at 128^2 tiles — deletes ds_writes + the
// VGPR round-trip, common-mistake #1). Round-14 verified the XOR read
// swizzle kills bank conflicts (6.29M -> 0); per rule #21 it is kept
// via linear LDS dest + INVERSE-swizzled global SOURCE column (XOR is
// an involution): LDS[r][c] = A[r][c^((r>>1)&3)], read at
// fqs = fq^((row>>1)&3) -> A[row][fq]. Staging writes are linear
// (lane*16B) = conflict-free. Sync is plain __syncthreads() (vmcnt
// drain before barrier) — the m97 structure, measured 874-912 TF.
// ------------------------------------------------------------------
enum { EPI_QKV = 1, EPI_BIAS_RELU = 3, EPI_PART = 6 };

#define BM 128
#define BK 32

template <int EPI, int TBN>
__global__ __launch_bounds__(256)
void gemm_bt(const bf16_t* __restrict__ A, int lda,
             const bf16_t* __restrict__ BT, int ldb,
             bf16_t* __restrict__ Cb, bf16_t* __restrict__ Cb2,
             const float* __restrict__ bias,
             int M, int N, int Ks) {
  __shared__ bf16_t sA[2][BM][BK];
  __shared__ bf16_t sB[2][TBN][BK];
  const int tid  = threadIdx.x;
  int lin = blockIdx.x + gridDim.x * (blockIdx.y + gridDim.y * blockIdx.z);
  const int by_ = lin % gridDim.y; lin /= gridDim.y;
  const int bx_ = lin % gridDim.x;
  const int bz_ = lin / gridDim.x;
  const int m0   = by_ * BM;
  const int n0   = bx_ * TBN;
  const long koff = (long)bz_ * Ks;
  const int lane = tid & 63, wave = tid >> 6;
  constexpr int MI = (TBN == 128) ? 4 : 2;
  const int wm = (TBN == 128) ? (wave >> 1) * 64 : wave * 32;
  const int wn = (TBN == 128) ? (wave & 1) * 64 : 0;
  const int fm = lane & 15, fq = lane >> 4;

  const int lr = lane >> 2, lc = (lane & 3) * 8;
  // inverse-swizzled SOURCE column (involution) + swizzled READ column
  const int lcs = lc ^ (((lr >> 1) & 3) << 3);
  const int fqs = (fq * 8) ^ (((fm >> 1) & 3) << 3);

  const bf16_t* gA0 = &A[(long)(m0 + wave * 32 + lr) * lda + koff + lcs];
  const bf16_t* gA1 = gA0 + 16 * (long)lda;
  const int brow = (TBN == 128) ? wave * 32 : wave * 16;
  const bf16_t* gB0 = &BT[(long)(n0 + brow + lr) * ldb + koff + lcs];
  const bf16_t* gB1 = gB0 + 16 * (long)ldb;   // used only when TBN==128

  f32x4 acc[MI][4] = {};

  // prologue: tile 0 -> LDS buf0 (async)
  gl16(gA0, &sA[0][wave * 32][0]);
  gl16(gA1, &sA[0][wave * 32 + 16][0]);
  gl16(gB0, &sB[0][brow][0]);
  if constexpr (TBN == 128) gl16(gB1, &sB[0][wave * 32 + 16][0]);
  gA0 += BK; gA1 += BK; gB0 += BK; gB1 += BK;
  __syncthreads();   // drains vmcnt: tile 0 resident

  int p = 0;
  for (int k0 = 0; k0 < Ks; k0 += BK, p ^= 1) {
    if (k0 + BK < Ks) {            // issue tile k+1; lands during compute
      gl16(gA0, &sA[p ^ 1][wave * 32][0]);
      gl16(gA1, &sA[p ^ 1][wave * 32 + 16][0]);
      gl16(gB0, &sB[p ^ 1][brow][0]);
      if constexpr (TBN == 128) gl16(gB1, &sB[p ^ 1][wave * 32 + 16][0]);
      gA0 += BK; gA1 += BK; gB0 += BK; gB1 += BK;
    }
    bf16x8 af[MI], bfr[4];
    #pragma unroll
    for (int i = 0; i < MI; i++) af[i]  = *(const bf16x8*)&sA[p][wm + i * 16 + fm][fqs];
    #pragma unroll
    for (int j = 0; j < 4; j++)  bfr[j] = *(const bf16x8*)&sB[p][wn + j * 16 + fm][fqs];
    #pragma unroll
    for (int i = 0; i < MI; i++)
      #pragma unroll
      for (int j = 0; j < 4; j++)
        acc[i][j] = __builtin_amdgcn_mfma_f32_16x16x32_bf16(af[i], bfr[j], acc[i][j], 0, 0, 0);
    __syncthreads();               // drains the async loads + ds reads
  }

  #pragma unroll
  for (int i = 0; i < MI; i++) {
    #pragma unroll
    for (int j = 0; j < 4; j++) {
      const int mb = m0 + wm + i * 16 + fq * 4;
      const int n  = n0 + wn + j * 16 + fm;
      #pragma unroll
      for (int r = 0; r < 4; r++) {
        const int m = mb + r;
        float vv = acc[i][j][r];
        if constexpr (EPI == EPI_QKV) {
          const int mat = n >> 10, h_ = (n >> 6) & 15, d_ = n & 63;
          const int b_ = m >> 11, s_ = m & 2047;
          if (mat == 2) {
            Cb2[((long)(b_ * NHEAD + h_) * HD + d_) * SEQ + s_] = (bf16_t)vv;
          } else {
            Cb[(long)mat * (32L * SEQ * HD) + (((long)(b_ * NHEAD + h_)) * SEQ + s_) * HD + d_] = (bf16_t)vv;
          }
        } else if constexpr (EPI == EPI_BIAS_RELU) {
          Cb[(long)m * N + n] = (bf16_t)fmaxf(vv + bias[n], 0.0f);
        } else {  // EPI_PART
          bf16_t* P = bz_ ? Cb2 : Cb;
          P[(long)m * N + n] = (bf16_t)vv;
        }
      }
    }
  }
}

// ------------------------------------------------------------------
// Flash attention v8 (unchanged from round 11: flash out of top-5):
// v6 LDS staging + T14 next-tile register prefetch, hoisted staging
// addresses (p enters maps linearly: u=p / jd=p).
// ------------------------------------------------------------------
#define KVT 128

__device__ __forceinline__ int swz(int grp, int slot) {
  return (grp * 64 + (slot ^ ((slot >> 3) & 7) ^ (grp & 1))) * 8;
}

__global__ __launch_bounds__(256)
void flash_attn(const bf16_t* __restrict__ q, const bf16_t* __restrict__ k,
                const bf16_t* __restrict__ vt,
                bf16_t* __restrict__ O0, bf16_t* __restrict__ O1,
                float* __restrict__ l0, float* __restrict__ l1) {
  __shared__ bf16_t sK[16 * 64 * 8];   // 16 KB
  __shared__ bf16_t sV[16 * 64 * 8];   // 16 KB

  const int tid  = threadIdx.x;
  const int bh   = blockIdx.x & 31, qb = blockIdx.x >> 5;   // XCD-cluster
  const int b    = bh >> 4, h = bh & 15;
  const int lane = tid & 63, wave = tid >> 6;
  const int fm   = lane & 15, fq = lane >> 4;
  const int qw0  = qb * 128 + wave * 32;
  const int kvbase = blockIdx.y * (SEQ / 2);
  bf16_t* Op = blockIdx.y ? O1 : O0;
  float*  lp = blockIdx.y ? l1 : l0;

  const bf16_t* qh  = q  + (long)bh * SEQ * HD;
  const bf16_t* kh  = k  + (long)bh * SEQ * HD;
  const bf16_t* vth = vt + (long)bh * HD * SEQ;

  // Q prescaled by (1/8)*log2(e): scores feed exp2 directly
  bf16x8 bQ[2][2];
  #pragma unroll
  for (int qt = 0; qt < 2; qt++)
    #pragma unroll
    for (int kk = 0; kk < 2; kk++) {
      bf16x8 v = *(const bf16x8*)&qh[(long)(qw0 + qt * 16 + fm) * HD + kk * 32 + fq * 8];
      #pragma unroll
      for (int e = 0; e < 8; e++) v[e] = (bf16_t)((float)v[e] * 0.18033688f);
      bQ[qt][kk] = v;
    }

  // ones-fragment for MFMA row-sums (kv-permutation-invariant)
  bf16x8 ones;
  #pragma unroll
  for (int e = 0; e < 8; e++) ones[e] = (bf16_t)1.0f;

  // ---- loop-invariant staging addresses (v6 maps with u=p, jd=p) ----
  const int krow = tid >> 3;                     // 0..31
  const int kc0  = (tid & 7) * 8;
  const int kh2  = (krow >> 2) & 1;
  const int kfmw = ((krow >> 3) << 2) | (krow & 3);
  const int kkk  = (tid >> 2) & 1;
  const int kfq3 = tid & 3;
  const int oK0  = swz(kh2 * 2 + kkk, kfq3 * 16 + kfmw);   // p adds 2048 elems
  const bf16_t* pKs = kh + (long)(kvbase + krow) * HD + kc0;

  const int vd0  = tid >> 4;                     // 0..15
  const int vc0  = (tid & 15) * 8;
  const int vu   = vc0 >> 5;
  const int vslot = ((vc0 >> 3) & 3) * 16 + vd0;
  int oV[4];
  #pragma unroll
  for (int p = 0; p < 4; p++) oV[p] = swz(vu * 4 + p, vslot);
  const bf16_t* pVs = vth + (long)vd0 * SEQ + kvbase + vc0;

  // prologue: tile 0 -> regs
  bf16x8 rK[4], rV[4];
  #pragma unroll
  for (int p = 0; p < 4; p++) {
    rK[p] = *(const bf16x8*)(pKs + p * 32 * HD);
    rV[p] = *(const bf16x8*)(pVs + p * 16 * SEQ);
  }
  pKs += KVT * HD; pVs += KVT;

  f32x4 oA[4] = {}, oB[4] = {};
  f32x4 oLA = {}, oLB = {};
  constexpr int NIT = (SEQ / 2) / KVT;

  for (int it = 0; it < NIT; it++) {
    __syncthreads();                 // all waves done reading previous tile
    #pragma unroll
    for (int p = 0; p < 4; p++) {    // tile it: regs -> LDS (vmcnt waits here)
      *(bf16x8*)&sK[oK0 + p * 2048] = rK[p];
      *(bf16x8*)&sV[oV[p]]          = rV[p];
    }
    if (it + 1 < NIT) {              // issue tile it+1 loads; land during compute
      #pragma unroll
      for (int p = 0; p < 4; p++) {
        rK[p] = *(const bf16x8*)(pKs + p * 32 * HD);
        rV[p] = *(const bf16x8*)(pVs + p * 16 * SEQ);
      }
      pKs += KVT * HD; pVs += KVT;
    }
    __syncthreads();                 // tile it visible

    #pragma unroll
    for (int u = 0; u < 4; u++) {
      f32x4 stA[2], stB[2];
      #pragma unroll
      for (int h2 = 0; h2 < 2; h2++) {
        bf16x8 aK0 = *(const bf16x8*)&sK[swz((u * 2 + h2) * 2 + 0, lane)];
        bf16x8 aK1 = *(const bf16x8*)&sK[swz((u * 2 + h2) * 2 + 1, lane)];
        f32x4 z0 = {};
        z0 = __builtin_amdgcn_mfma_f32_16x16x32_bf16(aK0, bQ[0][0], z0, 0, 0, 0);
        stA[h2] = __builtin_amdgcn_mfma_f32_16x16x32_bf16(aK1, bQ[0][1], z0, 0, 0, 0);
        f32x4 z1 = {};
        z1 = __builtin_amdgcn_mfma_f32_16x16x32_bf16(aK0, bQ[1][0], z1, 0, 0, 0);
        stB[h2] = __builtin_amdgcn_mfma_f32_16x16x32_bf16(aK1, bQ[1][1], z1, 0, 0, 0);
      }
      bf16x8 pA, pB;
      #pragma unroll
      for (int h2 = 0; h2 < 2; h2++)
        #pragma unroll
        for (int r = 0; r < 4; r++) {
          pA[h2 * 4 + r] = (bf16_t)__builtin_amdgcn_exp2f(stA[h2][r]);
          pB[h2 * 4 + r] = (bf16_t)__builtin_amdgcn_exp2f(stB[h2][r]);
        }
      // row sums on the matrix pipe
      oLA = __builtin_amdgcn_mfma_f32_16x16x32_bf16(pA, ones, oLA, 0, 0, 0);
      oLB = __builtin_amdgcn_mfma_f32_16x16x32_bf16(pB, ones, oLB, 0, 0, 0);
      #pragma unroll
      for (int jd = 0; jd < 4; jd++) {
        bf16x8 bV = *(const bf16x8*)&sV[swz(u * 4 + jd, lane)];
        oA[jd] = __builtin_amdgcn_mfma_f32_16x16x32_bf16(pA, bV, oA[jd], 0, 0, 0);
        oB[jd] = __builtin_amdgcn_mfma_f32_16x16x32_bf16(pB, bV, oB[jd], 0, 0, 0);
      }
    }
  }

  // oLA/oLB: D[q][c] with all 16 cols equal; lane fm==0 holds q = fq*4+r
  if (fm == 0) {
    #pragma unroll
    for (int r = 0; r < 4; r++) {
      lp[(long)bh * SEQ + qw0 + fq * 4 + r]      = oLA[r];
      lp[(long)bh * SEQ + qw0 + 16 + fq * 4 + r] = oLB[r];
    }
  }

  #pragma unroll
  for (int r = 0; r < 4; r++) {
    const long rowA = ((long)b * SEQ + qw0 + fq * 4 + r) * DIM + h * HD;
    const long rowB = rowA + 16L * DIM;
    #pragma unroll
    for (int jd = 0; jd < 4; jd++) {
      Op[rowA + jd * 16 + fm] = (bf16_t)oA[jd][r];
      Op[rowB + jd * 16 + fm] = (bf16_t)oB[jd][r];
    }
  }
}

// ------------------------------------------------------------------
// ws layout — 65 MB (unchanged):
// ------------------------------------------------------------------
extern "C" void kernel_launch(void* const* d_in, const int* in_sizes, int n_in,
                              void* d_out, int out_size, void* d_ws, size_t ws_size,
                              hipStream_t stream) {
  (void)in_sizes; (void)n_in; (void)out_size; (void)ws_size;
  const float* x      = (const float*)d_in[0];
  const float* wq     = (const float*)d_in[2];
  const float* wk     = (const float*)d_in[3];
  const float* wv     = (const float*)d_in[4];
  const float* wo     = (const float*)d_in[5];
  const float* w_up   = (const float*)d_in[6];
  const float* b_up   = (const float*)d_in[7];
  const float* w_down = (const float*)d_in[8];
  const float* b_down = (const float*)d_in[9];
  const float* ln1a   = (const float*)d_in[10];
  const float* ln1b   = (const float*)d_in[11];
  const float* ln2a   = (const float*)d_in[12];
  const float* ln2b   = (const float*)d_in[13];

  char* ws = (char*)d_ws;
  const size_t MB = 1ull << 20;
  const size_t KB = 1ull << 10;
  float*  l0     = (float*)(ws);              // 256 KB
  float*  l1     = (float*)(ws + 256 * KB);   // 256 KB
  bf16_t* wqkvT  = (bf16_t*)(ws + 512 * KB);  // 6 MB
  bf16_t* woT    = (bf16_t*)(ws + 512 * KB + 6 * MB);  // 2 MB
  bf16_t* h      = (bf16_t*)(ws + 9 * MB);
  bf16_t* O0     = (bf16_t*)(ws + 9 * MB);
  bf16_t* attn   = (bf16_t*)(ws + 9 * MB);
  bf16_t* qkv    = (bf16_t*)(ws + 17 * MB);
  bf16_t* qd     = (bf16_t*)(ws + 17 * MB);
  bf16_t* kd     = (bf16_t*)(ws + 25 * MB);
  bf16_t* vtd    = (bf16_t*)(ws + 33 * MB);
  bf16_t* O1     = (bf16_t*)(ws + 41 * MB);
  bf16_t* p0_wo  = (bf16_t*)(ws + 17 * MB);
  bf16_t* p1_wo  = (bf16_t*)(ws + 25 * MB);
  bf16_t* x1b    = (bf16_t*)(ws + 41 * MB);
  bf16_t* h2     = (bf16_t*)(ws);
  bf16_t* wdownT = (bf16_t*)(ws + 49 * MB);
  bf16_t* wupT   = (bf16_t*)(ws + 57 * MB);
  bf16_t* ff1    = (bf16_t*)(ws + 9 * MB);
  bf16_t* p0_fd  = (bf16_t*)(ws);
  bf16_t* p1_fd  = (bf16_t*)(ws + 57 * MB);
  float*  outp   = (float*)d_out;

  const dim3 T(256);
  TP tp{wq, wk, wv, wo, w_up, w_down, wqkvT, wupT, wdownT};
  transpose_all<<<dim3(12288), T, 0, stream>>>(tp);

  layernorm_k<<<dim3(4096), T, 0, stream>>>(x, ln1a, ln1b, h);
  gemm_bt<EPI_QKV, 128><<<dim3(24, 32), T, 0, stream>>>(h, DIM, wqkvT, DIM, qkv, vtd,
                                                        nullptr, NTOK, 3072, DIM);
  flash_attn<<<dim3(512, 2), T, 0, stream>>>(qd, kd, vtd, O0, O1, l0, l1);
  combine_att<<<dim3(NTOK * DIM / 1024), T, 0, stream>>>(O1, l0, l1, attn);
  gemm_bt<EPI_PART, 64><<<dim3(16, 32, 2), T, 0, stream>>>(attn, DIM, woT, DIM, p0_wo, p1_wo,
                                                           nullptr, NTOK, DIM, DIM / 2);
  reduce_wo_ln<<<dim3(4096), T, 0, stream>>>(x, p0_wo, p1_wo, ln2a, ln2b, x1b, h2);
  gemm_bt<EPI_BIAS_RELU, 128><<<dim3(32, 32), T, 0, stream>>>(h2, DIM, wupT, DIM, ff1, nullptr,
                                                              b_up, NTOK, DFF, DIM);
  gemm_bt<EPI_PART, 64><<<dim3(16, 32, 2), T, 0, stream>>>(ff1, DFF, wdownT, DFF, p0_fd, p1_fd,
                                                           nullptr, NTOK, DIM, DFF / 2);
  reduce_fd<<<dim3(NTOK * DIM / 1024), T, 0, stream>>>(x1b, b_down, p0_fd, p1_fd, outp);
}